// Round 1
// baseline (1329.296 us; speedup 1.0000x reference)
//
#include <hip/hip_runtime.h>
#include <cstdint>
#include <cstddef>

#define NVv 192
#define NAa 64
#define TT 128
#define FDd 1024
#define CCc 128
#define EEe 262144
#define NNn 32768

typedef _Float16 f16x8 __attribute__((ext_vector_type(8)));
typedef float f32x4 __attribute__((ext_vector_type(4)));

// ---------------- zero fill ----------------
__global__ __launch_bounds__(256) void k_zero(float* __restrict__ p) {
    size_t i = (size_t)blockIdx.x * 1024 + (size_t)threadIdx.x * 4;
    float4 z = make_float4(0.f, 0.f, 0.f, 0.f);
    *(float4*)(p + i) = z;
}

// ---------------- generic GEMM: out[M,128] = op(A[M,K] @ B[K,128] + bias + addmat) ----------------
// f16 MFMA 16x16x32, fp32 accumulate. BM=64, BN=128, BK=32, 256 threads (4 waves).
__global__ __launch_bounds__(256) void k_gemm(
    const float* __restrict__ A, const float* __restrict__ B,
    const float* __restrict__ bias, const float* __restrict__ addmat,
    float* __restrict__ out, int M, int K, int do_relu, int do_accum)
{
    __shared__ _Float16 Al[64][40];    // +8 pad: 2-way bank alias only (free)
    __shared__ _Float16 Bl[128][40];   // B transposed tile: Bl[n][k]
    const int tid  = threadIdx.x;
    const int wave = tid >> 6;
    const int lane = tid & 63;
    const int m0   = blockIdx.x * 64;

    f32x4 acc[8];
#pragma unroll
    for (int i = 0; i < 8; ++i) acc[i] = (f32x4){0.f, 0.f, 0.f, 0.f};

    const int ar = tid >> 2;          // 0..63  A row
    const int ak = (tid & 3) * 8;     // 0..24  A k-offset
    const int bk = tid >> 3;          // 0..31  B k-row
    const int bn = (tid & 7) * 16;    // 0..112 B n-offset
    const int fr = wave * 16 + (lane & 15);
    const int fk = (lane >> 4) * 8;

    for (int k0 = 0; k0 < K; k0 += 32) {
        const float* asrc = A + (size_t)(m0 + ar) * K + (k0 + ak);
        float4 a0 = *(const float4*)asrc;
        float4 a1 = *(const float4*)(asrc + 4);
        _Float16* ad = &Al[ar][ak];
        ad[0] = (_Float16)a0.x; ad[1] = (_Float16)a0.y;
        ad[2] = (_Float16)a0.z; ad[3] = (_Float16)a0.w;
        ad[4] = (_Float16)a1.x; ad[5] = (_Float16)a1.y;
        ad[6] = (_Float16)a1.z; ad[7] = (_Float16)a1.w;

        const float* bsrc = B + (size_t)(k0 + bk) * 128 + bn;
#pragma unroll
        for (int i = 0; i < 16; ++i) Bl[bn + i][bk] = (_Float16)bsrc[i];

        __syncthreads();
        f16x8 af = *(const f16x8*)&Al[fr][fk];
#pragma unroll
        for (int nt = 0; nt < 8; ++nt) {
            f16x8 bf = *(const f16x8*)&Bl[nt * 16 + (lane & 15)][fk];
            acc[nt] = __builtin_amdgcn_mfma_f32_16x16x32_f16(af, bf, acc[nt], 0, 0, 0);
        }
        __syncthreads();
    }

    const int rbase = wave * 16 + (lane >> 4) * 4;
    const int cbase = lane & 15;
#pragma unroll
    for (int nt = 0; nt < 8; ++nt) {
        int col = nt * 16 + cbase;
        float bv = bias ? bias[col] : 0.f;
#pragma unroll
        for (int rr = 0; rr < 4; ++rr) {
            int gr = m0 + rbase + rr;
            if (gr >= M) continue;
            size_t o = (size_t)gr * 128 + col;
            float v = acc[nt][rr] + bv;
            if (addmat) v += addmat[o];
            if (do_relu) v = fmaxf(v, 0.f);
            if (do_accum) out[o] += v; else out[o] = v;
        }
    }
}

// ---------------- edge MLP second layer + masked relu-seg-max scatter ----------------
// r_e = relu(u[dst] + v[src] - v[dst])  (b1 folded into u)
// h_e = r_e @ W2 + b2 ; agg[dst] = max(agg[dst], max(h_e,0)) via uint atomicMax
__global__ __launch_bounds__(256) void k_edge_mlp(
    const float* __restrict__ U, const float* __restrict__ V,
    const float* __restrict__ W2, const float* __restrict__ b2,
    const int* __restrict__ esrc, const int* __restrict__ edst,
    const int* __restrict__ attr, int alo, int ahi,
    float* __restrict__ agg)
{
    __shared__ _Float16 Rl[64][136];    // r tile (64 edges x 128 k), padded
    __shared__ _Float16 W2l[128][136];  // W2 transposed: W2l[n][k]
    __shared__ float b2l[128];
    __shared__ int eS[64], eD[64], eM[64];

    const int tid  = threadIdx.x;
    const int wave = tid >> 6;
    const int lane = tid & 63;

    // stage W2^T (once per block)
    for (int i = 0; i < 64; ++i) {
        int idx = tid + i * 256;           // 16384 elements
        int k = idx >> 7, n = idx & 127;
        W2l[n][k] = (_Float16)W2[idx];
    }
    if (tid < 128) b2l[tid] = b2[tid];

    const int c    = tid & 127;
    const int half = tid >> 7;
    const int frow = wave * 16 + (lane & 15);
    const int fq   = (lane >> 4) * 8;
    const int rbase = wave * 16 + (lane >> 4) * 4;
    const int cbase = lane & 15;

    for (int tt = 0; tt < 4; ++tt) {
        const int e0 = (blockIdx.x * 4 + tt) * 64;
        __syncthreads();   // protects LDS reuse (also covers W2 staging on tt=0)
        if (tid < 64) {
            int e = e0 + tid;
            eS[tid] = esrc[e];
            eD[tid] = edst[e];
            int a = attr[e];
            eM[tid] = (a >= alo && a <= ahi) ? 1 : 0;
        }
        __syncthreads();
#pragma unroll
        for (int it = 0; it < 32; ++it) {
            int i = it * 2 + half;
            float r = 0.f;
            if (eM[i]) {
                int d = eD[i], s = eS[i];
                float val = U[(size_t)d * 128 + c] + V[(size_t)s * 128 + c]
                          - V[(size_t)d * 128 + c];
                r = fmaxf(val, 0.f);
            }
            Rl[i][c] = (_Float16)r;
        }
        __syncthreads();

        f32x4 acc[8];
#pragma unroll
        for (int i = 0; i < 8; ++i) acc[i] = (f32x4){0.f, 0.f, 0.f, 0.f};
#pragma unroll
        for (int t4 = 0; t4 < 4; ++t4) {
            f16x8 af = *(const f16x8*)&Rl[frow][t4 * 32 + fq];
#pragma unroll
            for (int nt = 0; nt < 8; ++nt) {
                f16x8 bf = *(const f16x8*)&W2l[nt * 16 + (lane & 15)][t4 * 32 + fq];
                acc[nt] = __builtin_amdgcn_mfma_f32_16x16x32_f16(af, bf, acc[nt], 0, 0, 0);
            }
        }
#pragma unroll
        for (int nt = 0; nt < 8; ++nt) {
            int col = nt * 16 + cbase;
#pragma unroll
            for (int rr = 0; rr < 4; ++rr) {
                int row = rbase + rr;
                if (eM[row]) {
                    float v = fmaxf(acc[nt][rr] + b2l[col], 0.f);
                    atomicMax((unsigned int*)&agg[(size_t)eD[row] * 128 + col],
                              __float_as_uint(v));
                }
            }
        }
    }
}

// ---------------- scatter: masked max of (x[dst]+x[src]) ----------------
__global__ __launch_bounds__(256) void k_vpa_max(
    const float* __restrict__ X, const int* __restrict__ esrc,
    const int* __restrict__ edst, const int* __restrict__ attr,
    float* __restrict__ xag)
{
    int gid = blockIdx.x * 256 + threadIdx.x;
    int e = gid >> 7, cc = gid & 127;
    if (attr[e] == -3) {
        int s = esrc[e], d = edst[e];
        float v = X[(size_t)d * 128 + cc] + X[(size_t)s * 128 + cc];
        v = fmaxf(v, 0.f);
        atomicMax((unsigned int*)&xag[(size_t)d * 128 + cc], __float_as_uint(v));
    }
}

// ---------------- scatter: masked sum of (a_res[src]*x[src] + x[dst]) ----------------
__global__ __launch_bounds__(256) void k_acv_sum(
    const float* __restrict__ X, const float* __restrict__ ares,
    const int* __restrict__ esrc, const int* __restrict__ edst,
    const int* __restrict__ attr, float* __restrict__ xv2)
{
    int gid = blockIdx.x * 256 + threadIdx.x;
    int e = gid >> 7, cc = gid & 127;
    if (attr[e] == 3) {
        int s = esrc[e], d = edst[e];
        float v = ares[s] * X[(size_t)s * 128 + cc] + X[(size_t)d * 128 + cc];
        atomicAdd(&xv2[(size_t)d * 128 + cc], v);
    }
}

// ---------------- scatter: masked sum of h[src] + count ----------------
__global__ __launch_bounds__(256) void k_sage_sum(
    const float* __restrict__ H, const int* __restrict__ esrc,
    const int* __restrict__ edst, const int* __restrict__ attr,
    int alo, int ahi, float* __restrict__ S, float* __restrict__ cnt)
{
    int gid = blockIdx.x * 256 + threadIdx.x;
    int e = gid >> 7, cc = gid & 127;
    int a = attr[e];
    if (a >= alo && a <= ahi) {
        int s = esrc[e], d = edst[e];
        atomicAdd(&S[(size_t)d * 128 + cc], H[(size_t)s * 128 + cc]);
        if (cc == 0) atomicAdd(&cnt[d], 1.f);
    }
}

// ---------------- fc: a_res = a @ fc_W + fc_b ----------------
__global__ __launch_bounds__(256) void k_fc(
    const float* __restrict__ A, const float* __restrict__ W,
    const float* __restrict__ b, float* __restrict__ ares)
{
    int node = blockIdx.x * 4 + (threadIdx.x >> 6);
    int lane = threadIdx.x & 63;
    const float* row = A + (size_t)node * 128;
    float v = row[lane] * W[lane] + row[lane + 64] * W[lane + 64];
#pragma unroll
    for (int off = 32; off > 0; off >>= 1) v += __shfl_down(v, off, 64);
    if (lane == 0) ares[node] = v + b[0];
}

// ---------------- elementwise relu ----------------
__global__ __launch_bounds__(256) void k_relu4(float* __restrict__ p) {
    size_t i = ((size_t)blockIdx.x * 256 + threadIdx.x) * 4;
    float4 v = *(float4*)(p + i);
    v.x = fmaxf(v.x, 0.f); v.y = fmaxf(v.y, 0.f);
    v.z = fmaxf(v.z, 0.f); v.w = fmaxf(v.w, 0.f);
    *(float4*)(p + i) = v;
}

// ---------------- mean: S /= max(cnt,1) in place ----------------
__global__ __launch_bounds__(256) void k_mean(float* __restrict__ S, const float* __restrict__ cnt) {
    size_t i = ((size_t)blockIdx.x * 256 + threadIdx.x) * 4;
    float inv = 1.f / fmaxf(cnt[i >> 7], 1.f);
    float4 v = *(float4*)(S + i);
    v.x *= inv; v.y *= inv; v.z *= inv; v.w *= inv;
    *(float4*)(S + i) = v;
}

// ---------------- final gather of main-speaker visual nodes ----------------
__global__ __launch_bounds__(256) void k_gather(
    const float* __restrict__ xo, const int* __restrict__ spk, float* __restrict__ out)
{
    int gid = blockIdx.x * 256 + threadIdx.x;
    int cc = gid & 127, t = (gid >> 7) & 127, g = gid >> 14;
    int node = g * (spk[0] * TT) + t;
    out[gid] = xo[(size_t)node * 128 + cc];
}

extern "C" void kernel_launch(void* const* d_in, const int* in_sizes, int n_in,
                              void* d_out, int out_size, void* d_ws, size_t ws_size,
                              hipStream_t stream)
{
    (void)in_sizes; (void)n_in; (void)out_size; (void)ws_size;
    const float* xv   = (const float*)d_in[0];
    const float* xa   = (const float*)d_in[1];
    const float* W011 = (const float*)d_in[2];
    const float* b011 = (const float*)d_in[3];
    const float* W012 = (const float*)d_in[4];
    const float* b012 = (const float*)d_in[5];
    const float* ecW1[4] = {(const float*)d_in[6],  (const float*)d_in[10],
                            (const float*)d_in[14], (const float*)d_in[18]};
    const float* ecb1[4] = {(const float*)d_in[7],  (const float*)d_in[11],
                            (const float*)d_in[15], (const float*)d_in[19]};
    const float* ecW2[4] = {(const float*)d_in[8],  (const float*)d_in[12],
                            (const float*)d_in[16], (const float*)d_in[20]};
    const float* ecb2[4] = {(const float*)d_in[9],  (const float*)d_in[13],
                            (const float*)d_in[17], (const float*)d_in[21]};
    const float* sageWl = (const float*)d_in[22];
    const float* sagebl = (const float*)d_in[23];
    const float* sageWr = (const float*)d_in[24];
    const float* fcW    = (const float*)d_in[25];
    const float* fcb    = (const float*)d_in[26];
    const int*   esrc   = (const int*)d_in[27];
    const int*   edst   = esrc + EEe;
    const int*   attr   = (const int*)d_in[28];
    const int*   spk    = (const int*)d_in[29];
    float* out = (float*)d_out;

    const size_t NC = (size_t)NNn * CCc;   // 4194304
    float* ws   = (float*)d_ws;
    float* X    = ws;                  // node features
    float* S1   = ws + 1 * NC;         // xa_g, then sage-sum buffer
    float* U    = ws + 2 * NC;         // u, then sage tmp
    float* V    = ws + 3 * NC;
    float* AH   = ws + 4 * NC;         // a, then per-branch h
    float* XV2  = ws + 5 * NC;
    float* XO   = ws + 6 * NC;
    float* ARES = ws + 7 * NC;         // 32768
    float* CNT  = ARES + NNn;          // 32768

    const int GE   = EEe * 128 / 256;  // 131072 blocks: per-(edge,channel) scatter
    const int GN   = NNn / 64;         // 512 blocks: node GEMM
    const int GNC  = (int)(NC / 1024); // 4096 blocks: elementwise

    // x = [xv @ W011 + b011 ; xa @ W012 + b012]
    k_gemm<<<NVv * TT / 64, 256, 0, stream>>>(xv, W011, b011, nullptr, X, NVv * TT, FDd, 0, 0);
    k_gemm<<<NAa * TT / 64, 256, 0, stream>>>(xa, W012, b012, nullptr,
                                              X + (size_t)NVv * TT * CCc, NAa * TT, FDd, 0, 0);
    // xa_g = relu(segmax(x[dst]+x[src], mask attr==-3))
    k_zero<<<GNC, 256, 0, stream>>>(S1);
    k_vpa_max<<<GE, 256, 0, stream>>>(X, esrc, edst, attr, S1);
    // EdgeConv A on xa_g, mask attr==-2
    k_gemm<<<GN, 256, 0, stream>>>(S1, ecW1[0], ecb1[0], nullptr, U, NNn, CCc, 0, 0);
    k_gemm<<<GN, 256, 0, stream>>>(S1, ecW1[0] + CCc * CCc, nullptr, nullptr, V, NNn, CCc, 0, 0);
    k_zero<<<GNC, 256, 0, stream>>>(AH);
    k_edge_mlp<<<EEe / 256, 256, 0, stream>>>(U, V, ecW2[0], ecb2[0], esrc, edst, attr, -2, -2, AH);
    // a_res = a @ fc_W + fc_b
    k_fc<<<NNn / 4, 256, 0, stream>>>(AH, fcW, fcb, ARES);
    // xv2 = relu(segsum(a_res[src]*x[src] + x[dst], mask attr==3))
    k_zero<<<GNC, 256, 0, stream>>>(XV2);
    k_acv_sum<<<GE, 256, 0, stream>>>(X, ARES, esrc, edst, attr, XV2);
    k_relu4<<<GNC, 256, 0, stream>>>(XV2);
    // three branches accumulate into xo
    k_zero<<<GNC, 256, 0, stream>>>(XO);
    const int mlo[3] = {0, -1, -1}, mhi[3] = {1, 0, 1};
    for (int b = 0; b < 3; ++b) {
        const float* W1 = ecW1[b + 1];
        k_gemm<<<GN, 256, 0, stream>>>(XV2, W1, ecb1[b + 1], nullptr, U, NNn, CCc, 0, 0);
        k_gemm<<<GN, 256, 0, stream>>>(XV2, W1 + CCc * CCc, nullptr, nullptr, V, NNn, CCc, 0, 0);
        k_zero<<<GNC, 256, 0, stream>>>(AH);
        k_edge_mlp<<<EEe / 256, 256, 0, stream>>>(U, V, ecW2[b + 1], ecb2[b + 1],
                                                  esrc, edst, attr, mlo[b], mhi[b], AH);
        // SAGE: mean of h[src] over masked in-edges
        k_zero<<<GNC, 256, 0, stream>>>(S1);
        k_zero<<<NNn / 1024, 256, 0, stream>>>(CNT);
        k_sage_sum<<<GE, 256, 0, stream>>>(AH, esrc, edst, attr, mlo[b], mhi[b], S1, CNT);
        k_mean<<<GNC, 256, 0, stream>>>(S1, CNT);
        // xo += relu(mean@Wl + bl + h@Wr)
        k_gemm<<<GN, 256, 0, stream>>>(S1, sageWl, sagebl, nullptr, U, NNn, CCc, 0, 0);
        k_gemm<<<GN, 256, 0, stream>>>(AH, sageWr, nullptr, U, XO, NNn, CCc, 1, 1);
    }
    // gather main-speaker visual nodes
    k_gather<<<out_size / 256, 256, 0, stream>>>(XO, spk, out);
}

// Round 2
// 1221.538 us; speedup vs baseline: 1.0882x; 1.0882x over previous
//
#include <hip/hip_runtime.h>
#include <cstdint>
#include <cstddef>

#define NVv 192
#define NAa 64
#define TT 128
#define FDd 1024
#define CCc 128
#define EEe 262144
#define NNn 32768

typedef _Float16 f16x8 __attribute__((ext_vector_type(8)));
typedef float f32x4 __attribute__((ext_vector_type(4)));

// list arena capacities/offsets (int2 units): vpa, aud, acv, m1, m2, m3
#define CAP0 65536
#define CAP1 65536
#define CAP2 65536
#define CAP3 98304
#define CAP4 98304
#define CAP5 147456
#define ARENA_TOTAL (CAP0+CAP1+CAP2+CAP3+CAP4+CAP5)   // 540672

// ---------------- zero fill (1024 floats / block) ----------------
__global__ __launch_bounds__(256) void k_zero(float* __restrict__ p) {
    size_t i = (size_t)blockIdx.x * 1024 + (size_t)threadIdx.x * 4;
    *(float4*)(p + i) = make_float4(0.f, 0.f, 0.f, 0.f);
}

__global__ __launch_bounds__(64) void k_zero_cnts(int* __restrict__ c) {
    if (threadIdx.x < 8) c[threadIdx.x] = 0;
}

// ---------------- weight prep: f32 [K][128] -> f16 transposed [128][K] ----------------
__global__ __launch_bounds__(256) void k_wprep_big(
    const float* __restrict__ W011, const float* __restrict__ W012,
    _Float16* __restrict__ dst)
{
    int idx = blockIdx.x * 256 + threadIdx.x;        // 262144
    int which = idx >> 17;
    int r = idx & 131071;
    int n = r >> 10, k = r & 1023;
    const float* src = which ? W012 : W011;
    dst[idx] = (_Float16)src[k * 128 + n];
}

struct WSmall { const float* p[14]; };

__global__ __launch_bounds__(256) void k_wprep_small(WSmall ws, _Float16* __restrict__ dst)
{
    int idx = blockIdx.x * 256 + threadIdx.x;        // 14*16384 = 229376
    int seg = idx >> 14;
    int r = idx & 16383;
    int n = r >> 7, k = r & 127;
    const float* src = ws.p[seg];
    float v = src[k * 128 + n];
    if (seg < 12 && (seg % 3) == 0) v -= src[16384 + k * 128 + n];  // W1diff
    dst[idx] = (_Float16)v;
}

// ---------------- edge compaction into 6 masked lists ----------------
__global__ __launch_bounds__(256) void k_compact(
    const int* __restrict__ esrc, const int* __restrict__ edst,
    const int* __restrict__ attr, int2* __restrict__ arena, int* __restrict__ cnts)
{
    int e = blockIdx.x * 256 + threadIdx.x;
    int a = attr[e];
    int s = esrc[e], d = edst[e];
    int lane = threadIdx.x & 63;
    const int caps[6] = {CAP0, CAP1, CAP2, CAP3, CAP4, CAP5};
    const int offs[6] = {0, CAP0, CAP0+CAP1, CAP0+CAP1+CAP2,
                         CAP0+CAP1+CAP2+CAP3, CAP0+CAP1+CAP2+CAP3+CAP4};
    bool m[6];
    m[0] = (a == -3); m[1] = (a == -2); m[2] = (a == 3);
    m[3] = (a >= 0) & (a <= 1);
    m[4] = (a >= -1) & (a <= 0);
    m[5] = (a >= -1) & (a <= 1);
#pragma unroll
    for (int j = 0; j < 6; ++j) {
        unsigned long long b = __ballot(m[j]);
        if (b == 0) continue;                         // wave-uniform
        int leader = __ffsll((unsigned long long)b) - 1;
        int base = 0;
        if (lane == leader) base = atomicAdd(&cnts[j], (int)__popcll(b));
        base = __shfl(base, leader, 64);
        if (m[j]) {
            int pos = base + (int)__popcll(b & ((1ull << lane) - 1ull));
            if (pos < caps[j]) arena[offs[j] + pos] = make_int2(s, d);
        }
    }
}

// ---------------- generic GEMM: out[M,128] = op(A[M,K] @ BT^T + bias (+addmat)) ----------------
// BT is f16, pre-transposed [128][K]. Optional second B (BT2 -> out2, no bias).
__global__ __launch_bounds__(256) void k_gemm(
    const float* __restrict__ A, const _Float16* __restrict__ BT,
    const float* __restrict__ bias, const float* __restrict__ addmat,
    float* __restrict__ out,
    const _Float16* __restrict__ BT2, float* __restrict__ out2,
    int M, int K, int do_relu, int do_accum)
{
    __shared__ _Float16 Al[64][40];     // stride 80B (16B-aligned rows)
    __shared__ _Float16 Bl[128][40];
    __shared__ _Float16 Bl2[128][40];
    const int tid  = threadIdx.x;
    const int wave = tid >> 6;
    const int lane = tid & 63;
    const int m0   = blockIdx.x * 64;

    f32x4 acc[8], acc2[8];
#pragma unroll
    for (int i = 0; i < 8; ++i) { acc[i] = (f32x4){0,0,0,0}; acc2[i] = (f32x4){0,0,0,0}; }

    const int ar = tid >> 2;           // A row 0..63
    const int ak = (tid & 3) * 8;      // A k-off
    const int fr = wave * 16 + (lane & 15);
    const int fk = (lane >> 4) * 8;

    for (int k0 = 0; k0 < K; k0 += 32) {
        const float* asrc = A + (size_t)(m0 + ar) * K + (k0 + ak);
        float4 a0 = *(const float4*)asrc;
        float4 a1 = *(const float4*)(asrc + 4);
        f16x8 av = { (_Float16)a0.x, (_Float16)a0.y, (_Float16)a0.z, (_Float16)a0.w,
                     (_Float16)a1.x, (_Float16)a1.y, (_Float16)a1.z, (_Float16)a1.w };
        *(f16x8*)&Al[ar][ak] = av;
#pragma unroll
        for (int i = 0; i < 2; ++i) {
            int c = tid + i * 256;     // 512 chunks of 8
            int n = c >> 2, koff = (c & 3) * 8;
            *(f16x8*)&Bl[n][koff] = *(const f16x8*)(BT + (size_t)n * K + k0 + koff);
            if (BT2)
                *(f16x8*)&Bl2[n][koff] = *(const f16x8*)(BT2 + (size_t)n * K + k0 + koff);
        }
        __syncthreads();
        f16x8 af = *(const f16x8*)&Al[fr][fk];
#pragma unroll
        for (int nt = 0; nt < 8; ++nt) {
            f16x8 bf = *(const f16x8*)&Bl[nt * 16 + (lane & 15)][fk];
            acc[nt] = __builtin_amdgcn_mfma_f32_16x16x32_f16(af, bf, acc[nt], 0, 0, 0);
        }
        if (BT2) {
#pragma unroll
            for (int nt = 0; nt < 8; ++nt) {
                f16x8 bf = *(const f16x8*)&Bl2[nt * 16 + (lane & 15)][fk];
                acc2[nt] = __builtin_amdgcn_mfma_f32_16x16x32_f16(af, bf, acc2[nt], 0, 0, 0);
            }
        }
        __syncthreads();
    }

    const int rbase = wave * 16 + (lane >> 4) * 4;
    const int cbase = lane & 15;
#pragma unroll
    for (int nt = 0; nt < 8; ++nt) {
        int col = nt * 16 + cbase;
        float bv = bias ? bias[col] : 0.f;
#pragma unroll
        for (int rr = 0; rr < 4; ++rr) {
            int gr = m0 + rbase + rr;
            size_t o = (size_t)gr * 128 + col;
            float v = acc[nt][rr] + bv;
            if (addmat) v += addmat[o];
            if (do_relu) v = fmaxf(v, 0.f);
            if (do_accum) out[o] += v; else out[o] = v;
            if (BT2) out2[o] = acc2[nt][rr];
        }
    }
}

// ---------------- edge MLP (compacted): r = relu(P[d]+V[s]); agg[d] = max(agg[d], relu(r@W2+b2)) ----------------
__global__ __launch_bounds__(256, 3) void k_edge_mlp(
    const float* __restrict__ P, const float* __restrict__ V,
    const _Float16* __restrict__ W2T, const float* __restrict__ b2,
    const int2* __restrict__ list, const int* __restrict__ cntp, int cap,
    float* __restrict__ agg)
{
    __shared__ _Float16 Rl[64][136];
    __shared__ _Float16 W2l[128][136];
    __shared__ float b2l[128];
    __shared__ int2 eSD[64];
    __shared__ int eM[64];

    int cnt = min(*cntp, cap);
    int ntiles = (cnt + 63) >> 6;
    if ((int)blockIdx.x >= ntiles) return;

    const int tid  = threadIdx.x;
    const int wave = tid >> 6;
    const int lane = tid & 63;

    // stage W2^T (f16, pre-transposed [n][k]) once per block
#pragma unroll
    for (int i = 0; i < 8; ++i) {
        int c = tid + i * 256;               // 2048 chunks of 8
        int n = c >> 4, koff = (c & 15) * 8;
        *(f16x8*)&W2l[n][koff] = *(const f16x8*)(W2T + n * 128 + koff);
    }
    if (tid < 128) b2l[tid] = b2[tid];

    const int c     = tid & 127;
    const int half  = tid >> 7;
    const int frow  = wave * 16 + (lane & 15);
    const int fq    = (lane >> 4) * 8;
    const int rbase = wave * 16 + (lane >> 4) * 4;
    const int cbase = lane & 15;

    for (int t = blockIdx.x; t < ntiles; t += gridDim.x) {
        __syncthreads();                     // protect LDS reuse (covers W2 stage on first iter)
        if (tid < 64) {
            int e = t * 64 + tid;
            if (e < cnt) { eSD[tid] = list[e]; eM[tid] = 1; }
            else eM[tid] = 0;
        }
        __syncthreads();
#pragma unroll
        for (int it = 0; it < 32; ++it) {
            int i = it * 2 + half;
            float r = 0.f;
            if (eM[i]) {
                int2 sd = eSD[i];
                r = fmaxf(P[(size_t)sd.y * 128 + c] + V[(size_t)sd.x * 128 + c], 0.f);
            }
            Rl[i][c] = (_Float16)r;
        }
        __syncthreads();

        f32x4 acc[8];
#pragma unroll
        for (int i = 0; i < 8; ++i) acc[i] = (f32x4){0,0,0,0};
#pragma unroll
        for (int t4 = 0; t4 < 4; ++t4) {
            f16x8 af = *(const f16x8*)&Rl[frow][t4 * 32 + fq];
#pragma unroll
            for (int nt = 0; nt < 8; ++nt) {
                f16x8 bf = *(const f16x8*)&W2l[nt * 16 + (lane & 15)][t4 * 32 + fq];
                acc[nt] = __builtin_amdgcn_mfma_f32_16x16x32_f16(af, bf, acc[nt], 0, 0, 0);
            }
        }
#pragma unroll
        for (int nt = 0; nt < 8; ++nt) {
            int col = nt * 16 + cbase;
#pragma unroll
            for (int rr = 0; rr < 4; ++rr) {
                int row = rbase + rr;
                if (eM[row]) {
                    float v = fmaxf(acc[nt][rr] + b2l[col], 0.f);
                    atomicMax((unsigned int*)&agg[(size_t)eSD[row].y * 128 + col],
                              __float_as_uint(v));
                }
            }
        }
    }
}

// ---------------- compacted scatters (grid-stride) ----------------
__global__ __launch_bounds__(256) void k_vpa_max(
    const float* __restrict__ X, const int2* __restrict__ list,
    const int* __restrict__ cntp, int cap, float* __restrict__ xag)
{
    int cnt = min(*cntp, cap);
    int total = cnt << 7;
    for (int i = blockIdx.x * 256 + threadIdx.x; i < total; i += gridDim.x * 256) {
        int e = i >> 7, cc = i & 127;
        int2 sd = list[e];
        float v = X[(size_t)sd.y * 128 + cc] + X[(size_t)sd.x * 128 + cc];
        v = fmaxf(v, 0.f);
        atomicMax((unsigned int*)&xag[(size_t)sd.y * 128 + cc], __float_as_uint(v));
    }
}

__global__ __launch_bounds__(256) void k_acv_sum(
    const float* __restrict__ X, const float* __restrict__ ares,
    const int2* __restrict__ list, const int* __restrict__ cntp, int cap,
    float* __restrict__ xv2)
{
    int cnt = min(*cntp, cap);
    int total = cnt << 7;
    for (int i = blockIdx.x * 256 + threadIdx.x; i < total; i += gridDim.x * 256) {
        int e = i >> 7, cc = i & 127;
        int2 sd = list[e];
        float v = ares[sd.x] * X[(size_t)sd.x * 128 + cc] + X[(size_t)sd.y * 128 + cc];
        atomicAdd(&xv2[(size_t)sd.y * 128 + cc], v);
    }
}

__global__ __launch_bounds__(256) void k_sage_sum(
    const float* __restrict__ H, const int2* __restrict__ list,
    const int* __restrict__ cntp, int cap,
    float* __restrict__ S, float* __restrict__ cntN)
{
    int cnt = min(*cntp, cap);
    int total = cnt << 7;
    for (int i = blockIdx.x * 256 + threadIdx.x; i < total; i += gridDim.x * 256) {
        int e = i >> 7, cc = i & 127;
        int2 sd = list[e];
        atomicAdd(&S[(size_t)sd.y * 128 + cc], H[(size_t)sd.x * 128 + cc]);
        if (cc == 0) atomicAdd(&cntN[sd.y], 1.f);
    }
}

// ---------------- fc: a_res = a @ fc_W + fc_b ----------------
__global__ __launch_bounds__(256) void k_fc(
    const float* __restrict__ A, const float* __restrict__ W,
    const float* __restrict__ b, float* __restrict__ ares)
{
    int node = blockIdx.x * 4 + (threadIdx.x >> 6);
    int lane = threadIdx.x & 63;
    const float* row = A + (size_t)node * 128;
    float v = row[lane] * W[lane] + row[lane + 64] * W[lane + 64];
#pragma unroll
    for (int off = 32; off > 0; off >>= 1) v += __shfl_down(v, off, 64);
    if (lane == 0) ares[node] = v + b[0];
}

__global__ __launch_bounds__(256) void k_relu4(float* __restrict__ p) {
    size_t i = ((size_t)blockIdx.x * 256 + threadIdx.x) * 4;
    float4 v = *(float4*)(p + i);
    v.x = fmaxf(v.x, 0.f); v.y = fmaxf(v.y, 0.f);
    v.z = fmaxf(v.z, 0.f); v.w = fmaxf(v.w, 0.f);
    *(float4*)(p + i) = v;
}

__global__ __launch_bounds__(256) void k_mean(float* __restrict__ S, const float* __restrict__ cnt) {
    size_t i = ((size_t)blockIdx.x * 256 + threadIdx.x) * 4;
    float inv = 1.f / fmaxf(cnt[i >> 7], 1.f);
    float4 v = *(float4*)(S + i);
    v.x *= inv; v.y *= inv; v.z *= inv; v.w *= inv;
    *(float4*)(S + i) = v;
}

__global__ __launch_bounds__(256) void k_gather(
    const float* __restrict__ xo, const int* __restrict__ spk, float* __restrict__ out)
{
    int gid = blockIdx.x * 256 + threadIdx.x;
    int cc = gid & 127, t = (gid >> 7) & 127, g = gid >> 14;
    int node = g * (spk[0] * TT) + t;
    out[gid] = xo[(size_t)node * 128 + cc];
}

extern "C" void kernel_launch(void* const* d_in, const int* in_sizes, int n_in,
                              void* d_out, int out_size, void* d_ws, size_t ws_size,
                              hipStream_t stream)
{
    (void)in_sizes; (void)n_in; (void)ws_size;
    const float* xv   = (const float*)d_in[0];
    const float* xa   = (const float*)d_in[1];
    const float* W011 = (const float*)d_in[2];
    const float* b011 = (const float*)d_in[3];
    const float* W012 = (const float*)d_in[4];
    const float* b012 = (const float*)d_in[5];
    const float* ecW1[4] = {(const float*)d_in[6],  (const float*)d_in[10],
                            (const float*)d_in[14], (const float*)d_in[18]};
    const float* ecb1[4] = {(const float*)d_in[7],  (const float*)d_in[11],
                            (const float*)d_in[15], (const float*)d_in[19]};
    const float* ecW2[4] = {(const float*)d_in[8],  (const float*)d_in[12],
                            (const float*)d_in[16], (const float*)d_in[20]};
    const float* ecb2[4] = {(const float*)d_in[9],  (const float*)d_in[13],
                            (const float*)d_in[17], (const float*)d_in[21]};
    const float* sageWl = (const float*)d_in[22];
    const float* sagebl = (const float*)d_in[23];
    const float* sageWr = (const float*)d_in[24];
    const float* fcW    = (const float*)d_in[25];
    const float* fcb    = (const float*)d_in[26];
    const int*   esrc   = (const int*)d_in[27];
    const int*   edst   = esrc + EEe;
    const int*   attr   = (const int*)d_in[28];
    const int*   spk    = (const int*)d_in[29];
    float* out = (float*)d_out;

    const size_t NC = (size_t)NNn * CCc;
    float* ws   = (float*)d_ws;
    float* X    = ws;
    float* S1   = ws + 1 * NC;    // vpa out / sage-sum buffer (adjacent to AH for fused zero)
    float* AH   = ws + 2 * NC;    // edge-mlp aggregate
    float* P    = ws + 3 * NC;    // u - v (b1 folded)
    float* V    = ws + 4 * NC;
    float* XV2  = ws + 5 * NC;
    float* XO   = ws + 6 * NC;
    float* ARES = ws + 7 * NC;            // 32768
    float* CNTN = ARES + NNn;             // 32768
    int*   cnts = (int*)(CNTN + NNn);     // 8 ints (+pad)
    int2*  arena = (int2*)(CNTN + NNn + 16);
    _Float16* WT = (_Float16*)(arena + ARENA_TOTAL);

    const int2* L_vpa = arena;
    const int2* L_aud = arena + CAP0;
    const int2* L_acv = arena + CAP0 + CAP1;
    const int2* L_m[3] = { arena + CAP0 + CAP1 + CAP2,
                           arena + CAP0 + CAP1 + CAP2 + CAP3,
                           arena + CAP0 + CAP1 + CAP2 + CAP3 + CAP4 };
    const int capm[3] = {CAP3, CAP4, CAP5};

    const _Float16* W011T = WT;
    const _Float16* W012T = WT + 131072;
    const _Float16* WTs   = WT + 262144;   // 14 x 16384: [diff,b,W2] x4, Wl, Wr
    const _Float16* WlT   = WTs + 12 * 16384;
    const _Float16* WrT   = WTs + 13 * 16384;

    const int GN  = NNn / 64;          // 512
    const int GNC = (int)(NC / 1024);  // 4096

    // ---- weight prep + edge compaction ----
    k_wprep_big<<<1024, 256, 0, stream>>>(W011, W012, WT);
    WSmall wsm;
    for (int i = 0; i < 4; ++i) {
        wsm.p[3*i + 0] = ecW1[i];
        wsm.p[3*i + 1] = ecW1[i] + 16384;
        wsm.p[3*i + 2] = ecW2[i];
    }
    wsm.p[12] = sageWl; wsm.p[13] = sageWr;
    k_wprep_small<<<896, 256, 0, stream>>>(wsm, (_Float16*)WTs);
    k_zero_cnts<<<1, 64, 0, stream>>>(cnts);
    k_compact<<<EEe / 256, 256, 0, stream>>>(esrc, edst, attr, arena, cnts);

    // ---- x = [xv @ W011 + b011 ; xa @ W012 + b012] ----
    k_gemm<<<NVv * TT / 64, 256, 0, stream>>>(xv, W011T, b011, nullptr, X,
                                              nullptr, nullptr, NVv * TT, FDd, 0, 0);
    k_gemm<<<NAa * TT / 64, 256, 0, stream>>>(xa, W012T, b012, nullptr,
                                              X + (size_t)NVv * TT * CCc,
                                              nullptr, nullptr, NAa * TT, FDd, 0, 0);
    // ---- xa_g = relu(segmax(x[d]+x[s], attr==-3)) ----
    k_zero<<<2 * GNC, 256, 0, stream>>>(S1);    // S1 + AH
    k_vpa_max<<<2048, 256, 0, stream>>>(X, L_vpa, cnts + 0, CAP0, S1);
    // ---- EdgeConv A (attr==-2) ----
    k_gemm<<<GN, 256, 0, stream>>>(S1, WTs, ecb1[0], nullptr, P,
                                   WTs + 16384, V, NNn, CCc, 0, 0);
    k_edge_mlp<<<1024, 256, 0, stream>>>(P, V, WTs + 2 * 16384, ecb2[0],
                                         L_aud, cnts + 1, CAP1, AH);
    k_fc<<<NNn / 4, 256, 0, stream>>>(AH, fcW, fcb, ARES);
    // ---- xv2 = relu(segsum(ares[s]*x[s]+x[d], attr==3)) ----
    k_zero<<<2 * GNC, 256, 0, stream>>>(XV2);   // XV2 + XO
    k_acv_sum<<<2048, 256, 0, stream>>>(X, ARES, L_acv, cnts + 2, CAP2, XV2);
    k_relu4<<<GNC, 256, 0, stream>>>(XV2);
    // ---- three branches ----
    for (int b = 0; b < 3; ++b) {
        const _Float16* Wd = WTs + (3 * (b + 1)) * 16384;
        k_gemm<<<GN, 256, 0, stream>>>(XV2, Wd, ecb1[b + 1], nullptr, P,
                                       Wd + 16384, V, NNn, CCc, 0, 0);
        k_zero<<<2 * GNC, 256, 0, stream>>>(S1);             // S1 + AH
        k_zero<<<NNn / 1024, 256, 0, stream>>>(CNTN);
        k_edge_mlp<<<1024, 256, 0, stream>>>(P, V, Wd + 2 * 16384, ecb2[b + 1],
                                             L_m[b], cnts + 3 + b, capm[b], AH);
        k_sage_sum<<<2048, 256, 0, stream>>>(AH, L_m[b], cnts + 3 + b, capm[b], S1, CNTN);
        k_mean<<<GNC, 256, 0, stream>>>(S1, CNTN);
        k_gemm<<<GN, 256, 0, stream>>>(S1, WlT, sagebl, nullptr, P,
                                       nullptr, nullptr, NNn, CCc, 0, 0);
        k_gemm<<<GN, 256, 0, stream>>>(AH, WrT, nullptr, P, XO,
                                       nullptr, nullptr, NNn, CCc, 1, 1);
    }
    k_gather<<<out_size / 256, 256, 0, stream>>>(XO, spk, out);
}

// Round 3
// 942.381 us; speedup vs baseline: 1.4106x; 1.2962x over previous
//
#include <hip/hip_runtime.h>
#include <cstdint>
#include <cstddef>

#define NVv 192
#define NAa 64
#define TT 128
#define FDd 1024
#define CCc 128
#define EEe 262144
#define NNn 32768
#define NBLK (EEe / 256)   // 1024 compaction blocks

typedef _Float16 f16x8 __attribute__((ext_vector_type(8)));
typedef float f32x4 __attribute__((ext_vector_type(4)));

// list arena capacities/offsets (int2 units): vpa, aud, acv, m1, m2, m3
#define CAP0 65536
#define CAP1 65536
#define CAP2 65536
#define CAP3 98304
#define CAP4 98304
#define CAP5 147456
#define ARENA_TOTAL (CAP0+CAP1+CAP2+CAP3+CAP4+CAP5)   // 540672

__device__ __forceinline__ void eval_masks(int a, bool m[6]) {
    m[0] = (a == -3); m[1] = (a == -2); m[2] = (a == 3);
    m[3] = (a >= 0) & (a <= 1);
    m[4] = (a >= -1) & (a <= 0);
    m[5] = (a >= -1) & (a <= 1);
}

// ---------------- zero fill (1024 floats / block) ----------------
__global__ __launch_bounds__(256) void k_zero(float* __restrict__ p) {
    size_t i = (size_t)blockIdx.x * 1024 + (size_t)threadIdx.x * 4;
    *(float4*)(p + i) = make_float4(0.f, 0.f, 0.f, 0.f);
}

// ---------------- weight prep: f32 [K][128] -> f16 transposed [128][K] ----------------
__global__ __launch_bounds__(256) void k_wprep_big(
    const float* __restrict__ W011, const float* __restrict__ W012,
    _Float16* __restrict__ dst)
{
    int idx = blockIdx.x * 256 + threadIdx.x;        // 262144
    int which = idx >> 17;
    int r = idx & 131071;
    int n = r >> 10, k = r & 1023;
    const float* src = which ? W012 : W011;
    dst[idx] = (_Float16)src[k * 128 + n];
}

struct WSmall { const float* p[14]; };

__global__ __launch_bounds__(256) void k_wprep_small(WSmall ws, _Float16* __restrict__ dst)
{
    int idx = blockIdx.x * 256 + threadIdx.x;        // 14*16384 = 229376
    int seg = idx >> 14;
    int r = idx & 16383;
    int n = r >> 7, k = r & 127;
    const float* src = ws.p[seg];
    float v = src[k * 128 + n];
    if (seg < 12 && (seg % 3) == 0) v -= src[16384 + k * 128 + n];  // W1diff
    dst[idx] = (_Float16)v;
}

// ---------------- compaction phase 1: per-block mask histogram ----------------
__global__ __launch_bounds__(256) void k_count(
    const int* __restrict__ attr, int* __restrict__ bc)   // bc[NBLK][6]
{
    __shared__ int h[6];
    if (threadIdx.x < 6) h[threadIdx.x] = 0;
    __syncthreads();
    int a = attr[blockIdx.x * 256 + threadIdx.x];
    bool m[6]; eval_masks(a, m);
    int lane = threadIdx.x & 63;
#pragma unroll
    for (int j = 0; j < 6; ++j) {
        unsigned long long b = __ballot(m[j]);
        if (lane == 0) atomicAdd(&h[j], (int)__popcll(b));
    }
    __syncthreads();
    if (threadIdx.x < 6) bc[blockIdx.x * 6 + threadIdx.x] = h[threadIdx.x];
}

// ---------------- compaction phase 2: exclusive scan (1 block, wave per mask) ----------------
__global__ __launch_bounds__(384) void k_scan(int* __restrict__ bc, int* __restrict__ cnts)
{
    int wv = threadIdx.x >> 6;        // 0..5 = mask
    int lane = threadIdx.x & 63;
    int run = 0;
    for (int base = 0; base < NBLK; base += 64) {
        int v = bc[(base + lane) * 6 + wv];
        int x = v;
#pragma unroll
        for (int off = 1; off < 64; off <<= 1) {
            int y = __shfl_up(x, off, 64);
            if (lane >= off) x += y;
        }
        bc[(base + lane) * 6 + wv] = run + (x - v);   // exclusive
        run += __shfl(x, 63, 64);
    }
    if (lane == 0) cnts[wv] = run;
}

// ---------------- compaction phase 3: deterministic scatter, no atomics ----------------
__global__ __launch_bounds__(256) void k_scatter(
    const int* __restrict__ esrc, const int* __restrict__ edst,
    const int* __restrict__ attr, const int* __restrict__ bc,
    int2* __restrict__ arena)
{
    __shared__ int wbase[4][6];
    int e = blockIdx.x * 256 + threadIdx.x;
    int a = attr[e];
    int s = esrc[e], d = edst[e];
    int wave = threadIdx.x >> 6, lane = threadIdx.x & 63;
    bool m[6]; eval_masks(a, m);
    unsigned long long b[6];
#pragma unroll
    for (int j = 0; j < 6; ++j) b[j] = __ballot(m[j]);
    if (lane < 6) wbase[wave][lane] = (int)__popcll(b[lane]);
    __syncthreads();
    if (threadIdx.x < 6) {
        int j = threadIdx.x;
        int run = bc[blockIdx.x * 6 + j];
#pragma unroll
        for (int w = 0; w < 4; ++w) { int t = wbase[w][j]; wbase[w][j] = run; run += t; }
    }
    __syncthreads();
    const int caps[6] = {CAP0, CAP1, CAP2, CAP3, CAP4, CAP5};
    const int offs[6] = {0, CAP0, CAP0+CAP1, CAP0+CAP1+CAP2,
                         CAP0+CAP1+CAP2+CAP3, CAP0+CAP1+CAP2+CAP3+CAP4};
#pragma unroll
    for (int j = 0; j < 6; ++j) {
        if (m[j]) {
            int pos = wbase[wave][j] + (int)__popcll(b[j] & ((1ull << lane) - 1ull));
            if (pos < caps[j]) arena[offs[j] + pos] = make_int2(s, d);
        }
    }
}

// ---------------- generic GEMM: out[M,128] = op(A[M,K] @ BT^T + bias (+addmat)) ----------------
// BT is f16, pre-transposed [128][K]. Optional second B (BT2 -> out2, no bias).
__global__ __launch_bounds__(256) void k_gemm(
    const float* __restrict__ A, const _Float16* __restrict__ BT,
    const float* __restrict__ bias, const float* __restrict__ addmat,
    float* __restrict__ out,
    const _Float16* __restrict__ BT2, float* __restrict__ out2,
    int M, int K, int do_relu, int do_accum)
{
    __shared__ _Float16 Al[64][40];
    __shared__ _Float16 Bl[128][40];
    __shared__ _Float16 Bl2[128][40];
    const int tid  = threadIdx.x;
    const int wave = tid >> 6;
    const int lane = tid & 63;
    const int m0   = blockIdx.x * 64;

    f32x4 acc[8], acc2[8];
#pragma unroll
    for (int i = 0; i < 8; ++i) { acc[i] = (f32x4){0,0,0,0}; acc2[i] = (f32x4){0,0,0,0}; }

    const int ar = tid >> 2;
    const int ak = (tid & 3) * 8;
    const int fr = wave * 16 + (lane & 15);
    const int fk = (lane >> 4) * 8;

    for (int k0 = 0; k0 < K; k0 += 32) {
        const float* asrc = A + (size_t)(m0 + ar) * K + (k0 + ak);
        float4 a0 = *(const float4*)asrc;
        float4 a1 = *(const float4*)(asrc + 4);
        f16x8 av = { (_Float16)a0.x, (_Float16)a0.y, (_Float16)a0.z, (_Float16)a0.w,
                     (_Float16)a1.x, (_Float16)a1.y, (_Float16)a1.z, (_Float16)a1.w };
        *(f16x8*)&Al[ar][ak] = av;
#pragma unroll
        for (int i = 0; i < 2; ++i) {
            int c = tid + i * 256;
            int n = c >> 2, koff = (c & 3) * 8;
            *(f16x8*)&Bl[n][koff] = *(const f16x8*)(BT + (size_t)n * K + k0 + koff);
            if (BT2)
                *(f16x8*)&Bl2[n][koff] = *(const f16x8*)(BT2 + (size_t)n * K + k0 + koff);
        }
        __syncthreads();
        f16x8 af = *(const f16x8*)&Al[fr][fk];
#pragma unroll
        for (int nt = 0; nt < 8; ++nt) {
            f16x8 bf = *(const f16x8*)&Bl[nt * 16 + (lane & 15)][fk];
            acc[nt] = __builtin_amdgcn_mfma_f32_16x16x32_f16(af, bf, acc[nt], 0, 0, 0);
        }
        if (BT2) {
#pragma unroll
            for (int nt = 0; nt < 8; ++nt) {
                f16x8 bf = *(const f16x8*)&Bl2[nt * 16 + (lane & 15)][fk];
                acc2[nt] = __builtin_amdgcn_mfma_f32_16x16x32_f16(af, bf, acc2[nt], 0, 0, 0);
            }
        }
        __syncthreads();
    }

    const int rbase = wave * 16 + (lane >> 4) * 4;
    const int cbase = lane & 15;
#pragma unroll
    for (int nt = 0; nt < 8; ++nt) {
        int col = nt * 16 + cbase;
        float bv = bias ? bias[col] : 0.f;
#pragma unroll
        for (int rr = 0; rr < 4; ++rr) {
            int gr = m0 + rbase + rr;
            size_t o = (size_t)gr * 128 + col;
            float v = acc[nt][rr] + bv;
            if (addmat) v += addmat[o];
            if (do_relu) v = fmaxf(v, 0.f);
            if (do_accum) out[o] += v; else out[o] = v;
            if (BT2) out2[o] = acc2[nt][rr];
        }
    }
}

// ---------------- edge MLP (compacted): r = relu(P[d]+V[s]); agg[d] = max(agg[d], relu(r@W2+b2)) ----------------
__global__ __launch_bounds__(256, 3) void k_edge_mlp(
    const float* __restrict__ P, const float* __restrict__ V,
    const _Float16* __restrict__ W2T, const float* __restrict__ b2,
    const int2* __restrict__ list, const int* __restrict__ cntp, int cap,
    float* __restrict__ agg)
{
    __shared__ _Float16 Rl[64][136];
    __shared__ _Float16 W2l[128][136];
    __shared__ float b2l[128];
    __shared__ int2 eSD[64];
    __shared__ int eM[64];

    int cnt = min(*cntp, cap);
    int ntiles = (cnt + 63) >> 6;
    if ((int)blockIdx.x >= ntiles) return;

    const int tid  = threadIdx.x;
    const int wave = tid >> 6;
    const int lane = tid & 63;

#pragma unroll
    for (int i = 0; i < 8; ++i) {
        int c = tid + i * 256;
        int n = c >> 4, koff = (c & 15) * 8;
        *(f16x8*)&W2l[n][koff] = *(const f16x8*)(W2T + n * 128 + koff);
    }
    if (tid < 128) b2l[tid] = b2[tid];

    const int c     = tid & 127;
    const int half  = tid >> 7;
    const int frow  = wave * 16 + (lane & 15);
    const int fq    = (lane >> 4) * 8;
    const int rbase = wave * 16 + (lane >> 4) * 4;
    const int cbase = lane & 15;

    for (int t = blockIdx.x; t < ntiles; t += gridDim.x) {
        __syncthreads();
        if (tid < 64) {
            int e = t * 64 + tid;
            if (e < cnt) { eSD[tid] = list[e]; eM[tid] = 1; }
            else eM[tid] = 0;
        }
        __syncthreads();
#pragma unroll
        for (int it = 0; it < 32; ++it) {
            int i = it * 2 + half;
            float r = 0.f;
            if (eM[i]) {
                int2 sd = eSD[i];
                r = fmaxf(P[(size_t)sd.y * 128 + c] + V[(size_t)sd.x * 128 + c], 0.f);
            }
            Rl[i][c] = (_Float16)r;
        }
        __syncthreads();

        f32x4 acc[8];
#pragma unroll
        for (int i = 0; i < 8; ++i) acc[i] = (f32x4){0,0,0,0};
#pragma unroll
        for (int t4 = 0; t4 < 4; ++t4) {
            f16x8 af = *(const f16x8*)&Rl[frow][t4 * 32 + fq];
#pragma unroll
            for (int nt = 0; nt < 8; ++nt) {
                f16x8 bf = *(const f16x8*)&W2l[nt * 16 + (lane & 15)][t4 * 32 + fq];
                acc[nt] = __builtin_amdgcn_mfma_f32_16x16x32_f16(af, bf, acc[nt], 0, 0, 0);
            }
        }
#pragma unroll
        for (int nt = 0; nt < 8; ++nt) {
            int col = nt * 16 + cbase;
#pragma unroll
            for (int rr = 0; rr < 4; ++rr) {
                int row = rbase + rr;
                if (eM[row]) {
                    float v = fmaxf(acc[nt][rr] + b2l[col], 0.f);
                    atomicMax((unsigned int*)&agg[(size_t)eSD[row].y * 128 + col],
                              __float_as_uint(v));
                }
            }
        }
    }
}

// ---------------- compacted scatters (grid-stride) ----------------
__global__ __launch_bounds__(256) void k_vpa_max(
    const float* __restrict__ X, const int2* __restrict__ list,
    const int* __restrict__ cntp, int cap, float* __restrict__ xag)
{
    int cnt = min(*cntp, cap);
    int total = cnt << 7;
    for (int i = blockIdx.x * 256 + threadIdx.x; i < total; i += gridDim.x * 256) {
        int e = i >> 7, cc = i & 127;
        int2 sd = list[e];
        float v = X[(size_t)sd.y * 128 + cc] + X[(size_t)sd.x * 128 + cc];
        v = fmaxf(v, 0.f);
        atomicMax((unsigned int*)&xag[(size_t)sd.y * 128 + cc], __float_as_uint(v));
    }
}

__global__ __launch_bounds__(256) void k_acv_sum(
    const float* __restrict__ X, const float* __restrict__ ares,
    const int2* __restrict__ list, const int* __restrict__ cntp, int cap,
    float* __restrict__ xv2)
{
    int cnt = min(*cntp, cap);
    int total = cnt << 7;
    for (int i = blockIdx.x * 256 + threadIdx.x; i < total; i += gridDim.x * 256) {
        int e = i >> 7, cc = i & 127;
        int2 sd = list[e];
        float v = ares[sd.x] * X[(size_t)sd.x * 128 + cc] + X[(size_t)sd.y * 128 + cc];
        atomicAdd(&xv2[(size_t)sd.y * 128 + cc], v);
    }
}

__global__ __launch_bounds__(256) void k_sage_sum(
    const float* __restrict__ H, const int2* __restrict__ list,
    const int* __restrict__ cntp, int cap,
    float* __restrict__ S, float* __restrict__ cntN)
{
    int cnt = min(*cntp, cap);
    int total = cnt << 7;
    for (int i = blockIdx.x * 256 + threadIdx.x; i < total; i += gridDim.x * 256) {
        int e = i >> 7, cc = i & 127;
        int2 sd = list[e];
        atomicAdd(&S[(size_t)sd.y * 128 + cc], H[(size_t)sd.x * 128 + cc]);
        if (cc == 0) atomicAdd(&cntN[sd.y], 1.f);
    }
}

// ---------------- fc: a_res = a @ fc_W + fc_b ----------------
__global__ __launch_bounds__(256) void k_fc(
    const float* __restrict__ A, const float* __restrict__ W,
    const float* __restrict__ b, float* __restrict__ ares)
{
    int node = blockIdx.x * 4 + (threadIdx.x >> 6);
    int lane = threadIdx.x & 63;
    const float* row = A + (size_t)node * 128;
    float v = row[lane] * W[lane] + row[lane + 64] * W[lane + 64];
#pragma unroll
    for (int off = 32; off > 0; off >>= 1) v += __shfl_down(v, off, 64);
    if (lane == 0) ares[node] = v + b[0];
}

__global__ __launch_bounds__(256) void k_relu4(float* __restrict__ p) {
    size_t i = ((size_t)blockIdx.x * 256 + threadIdx.x) * 4;
    float4 v = *(float4*)(p + i);
    v.x = fmaxf(v.x, 0.f); v.y = fmaxf(v.y, 0.f);
    v.z = fmaxf(v.z, 0.f); v.w = fmaxf(v.w, 0.f);
    *(float4*)(p + i) = v;
}

__global__ __launch_bounds__(256) void k_mean(float* __restrict__ S, const float* __restrict__ cnt) {
    size_t i = ((size_t)blockIdx.x * 256 + threadIdx.x) * 4;
    float inv = 1.f / fmaxf(cnt[i >> 7], 1.f);
    float4 v = *(float4*)(S + i);
    v.x *= inv; v.y *= inv; v.z *= inv; v.w *= inv;
    *(float4*)(S + i) = v;
}

__global__ __launch_bounds__(256) void k_gather(
    const float* __restrict__ xo, const int* __restrict__ spk, float* __restrict__ out)
{
    int gid = blockIdx.x * 256 + threadIdx.x;
    int cc = gid & 127, t = (gid >> 7) & 127, g = gid >> 14;
    int node = g * (spk[0] * TT) + t;
    out[gid] = xo[(size_t)node * 128 + cc];
}

extern "C" void kernel_launch(void* const* d_in, const int* in_sizes, int n_in,
                              void* d_out, int out_size, void* d_ws, size_t ws_size,
                              hipStream_t stream)
{
    (void)in_sizes; (void)n_in; (void)ws_size;
    const float* xv   = (const float*)d_in[0];
    const float* xa   = (const float*)d_in[1];
    const float* W011 = (const float*)d_in[2];
    const float* b011 = (const float*)d_in[3];
    const float* W012 = (const float*)d_in[4];
    const float* b012 = (const float*)d_in[5];
    const float* ecW1[4] = {(const float*)d_in[6],  (const float*)d_in[10],
                            (const float*)d_in[14], (const float*)d_in[18]};
    const float* ecb1[4] = {(const float*)d_in[7],  (const float*)d_in[11],
                            (const float*)d_in[15], (const float*)d_in[19]};
    const float* ecW2[4] = {(const float*)d_in[8],  (const float*)d_in[12],
                            (const float*)d_in[16], (const float*)d_in[20]};
    const float* ecb2[4] = {(const float*)d_in[9],  (const float*)d_in[13],
                            (const float*)d_in[17], (const float*)d_in[21]};
    const float* sageWl = (const float*)d_in[22];
    const float* sagebl = (const float*)d_in[23];
    const float* sageWr = (const float*)d_in[24];
    const float* fcW    = (const float*)d_in[25];
    const float* fcb    = (const float*)d_in[26];
    const int*   esrc   = (const int*)d_in[27];
    const int*   edst   = esrc + EEe;
    const int*   attr   = (const int*)d_in[28];
    const int*   spk    = (const int*)d_in[29];
    float* out = (float*)d_out;

    const size_t NC = (size_t)NNn * CCc;
    float* ws   = (float*)d_ws;
    float* X    = ws;
    float* S1   = ws + 1 * NC;
    float* AH   = ws + 2 * NC;
    float* P    = ws + 3 * NC;
    float* V    = ws + 4 * NC;
    float* XV2  = ws + 5 * NC;
    float* XO   = ws + 6 * NC;
    float* ARES = ws + 7 * NC;            // 32768
    float* CNTN = ARES + NNn;             // 32768
    int*   cnts = (int*)(CNTN + NNn);     // 8 ints
    int*   bc   = cnts + 16;              // NBLK*6 block counts / offsets
    int2*  arena = (int2*)(bc + NBLK * 6 + 16);
    _Float16* WT = (_Float16*)(arena + ARENA_TOTAL);

    const int2* L_vpa = arena;
    const int2* L_aud = arena + CAP0;
    const int2* L_acv = arena + CAP0 + CAP1;
    const int2* L_m[3] = { arena + CAP0 + CAP1 + CAP2,
                           arena + CAP0 + CAP1 + CAP2 + CAP3,
                           arena + CAP0 + CAP1 + CAP2 + CAP3 + CAP4 };
    const int capm[3] = {CAP3, CAP4, CAP5};

    const _Float16* W011T = WT;
    const _Float16* W012T = WT + 131072;
    const _Float16* WTs   = WT + 262144;
    const _Float16* WlT   = WTs + 12 * 16384;
    const _Float16* WrT   = WTs + 13 * 16384;

    const int GN  = NNn / 64;          // 512
    const int GNC = (int)(NC / 1024);  // 4096

    // ---- weight prep + 3-phase compaction (no global atomics) ----
    k_wprep_big<<<1024, 256, 0, stream>>>(W011, W012, WT);
    WSmall wsm;
    for (int i = 0; i < 4; ++i) {
        wsm.p[3*i + 0] = ecW1[i];
        wsm.p[3*i + 1] = ecW1[i] + 16384;
        wsm.p[3*i + 2] = ecW2[i];
    }
    wsm.p[12] = sageWl; wsm.p[13] = sageWr;
    k_wprep_small<<<896, 256, 0, stream>>>(wsm, (_Float16*)WTs);
    k_count<<<NBLK, 256, 0, stream>>>(attr, bc);
    k_scan<<<1, 384, 0, stream>>>(bc, cnts);
    k_scatter<<<NBLK, 256, 0, stream>>>(esrc, edst, attr, bc, arena);

    // ---- x = [xv @ W011 + b011 ; xa @ W012 + b012] ----
    k_gemm<<<NVv * TT / 64, 256, 0, stream>>>(xv, W011T, b011, nullptr, X,
                                              nullptr, nullptr, NVv * TT, FDd, 0, 0);
    k_gemm<<<NAa * TT / 64, 256, 0, stream>>>(xa, W012T, b012, nullptr,
                                              X + (size_t)NVv * TT * CCc,
                                              nullptr, nullptr, NAa * TT, FDd, 0, 0);
    // ---- xa_g = relu(segmax(x[d]+x[s], attr==-3)) ----
    k_zero<<<2 * GNC, 256, 0, stream>>>(S1);    // S1 + AH
    k_vpa_max<<<2048, 256, 0, stream>>>(X, L_vpa, cnts + 0, CAP0, S1);
    // ---- EdgeConv A (attr==-2) ----
    k_gemm<<<GN, 256, 0, stream>>>(S1, WTs, ecb1[0], nullptr, P,
                                   WTs + 16384, V, NNn, CCc, 0, 0);
    k_edge_mlp<<<1024, 256, 0, stream>>>(P, V, WTs + 2 * 16384, ecb2[0],
                                         L_aud, cnts + 1, CAP1, AH);
    k_fc<<<NNn / 4, 256, 0, stream>>>(AH, fcW, fcb, ARES);
    // ---- xv2 = relu(segsum(ares[s]*x[s]+x[d], attr==3)) ----
    k_zero<<<2 * GNC, 256, 0, stream>>>(XV2);   // XV2 + XO
    k_acv_sum<<<2048, 256, 0, stream>>>(X, ARES, L_acv, cnts + 2, CAP2, XV2);
    k_relu4<<<GNC, 256, 0, stream>>>(XV2);
    // ---- three branches ----
    for (int b = 0; b < 3; ++b) {
        const _Float16* Wd = WTs + (3 * (b + 1)) * 16384;
        k_gemm<<<GN, 256, 0, stream>>>(XV2, Wd, ecb1[b + 1], nullptr, P,
                                       Wd + 16384, V, NNn, CCc, 0, 0);
        k_zero<<<2 * GNC, 256, 0, stream>>>(S1);             // S1 + AH
        k_zero<<<NNn / 1024, 256, 0, stream>>>(CNTN);
        k_edge_mlp<<<1024, 256, 0, stream>>>(P, V, Wd + 2 * 16384, ecb2[b + 1],
                                             L_m[b], cnts + 3 + b, capm[b], AH);
        k_sage_sum<<<2048, 256, 0, stream>>>(AH, L_m[b], cnts + 3 + b, capm[b], S1, CNTN);
        k_mean<<<GNC, 256, 0, stream>>>(S1, CNTN);
        k_gemm<<<GN, 256, 0, stream>>>(S1, WlT, sagebl, nullptr, P,
                                       nullptr, nullptr, NNn, CCc, 0, 0);
        k_gemm<<<GN, 256, 0, stream>>>(AH, WrT, nullptr, P, XO,
                                       nullptr, nullptr, NNn, CCc, 1, 1);
    }
    k_gather<<<out_size / 256, 256, 0, stream>>>(XO, spk, out);
}

// Round 4
// 885.794 us; speedup vs baseline: 1.5007x; 1.0639x over previous
//
#include <hip/hip_runtime.h>
#include <cstdint>
#include <cstddef>

#define NVv 192
#define NAa 64
#define TT 128
#define FDd 1024
#define CCc 128
#define EEe 262144
#define NNn 32768

typedef _Float16 f16x8 __attribute__((ext_vector_type(8)));
typedef float f32x4 __attribute__((ext_vector_type(4)));

// list arena capacities/offsets (int2 units): vpa, aud, acv, m1, m2, m3
#define CAP0 65536
#define CAP1 65536
#define CAP2 65536
#define CAP3 98304
#define CAP4 98304
#define CAP5 147456
#define ARENA_TOTAL (CAP0+CAP1+CAP2+CAP3+CAP4+CAP5)   // 540672

__device__ __forceinline__ void eval_masks(int a, bool m[6]) {
    m[0] = (a == -3); m[1] = (a == -2); m[2] = (a == 3);
    m[3] = (a >= 0) & (a <= 1);
    m[4] = (a >= -1) & (a <= 0);
    m[5] = (a >= -1) & (a <= 1);
}

// ---------------- zero fill (1024 floats / block) ----------------
__global__ __launch_bounds__(256) void k_zero(float* __restrict__ p) {
    size_t i = (size_t)blockIdx.x * 1024 + (size_t)threadIdx.x * 4;
    *(float4*)(p + i) = make_float4(0.f, 0.f, 0.f, 0.f);
}

// ---------------- weight prep: f32 [K][128] -> f16 transposed [128][K] ----------------
__global__ __launch_bounds__(256) void k_wprep_big(
    const float* __restrict__ W011, const float* __restrict__ W012,
    _Float16* __restrict__ dst)
{
    int idx = blockIdx.x * 256 + threadIdx.x;        // 262144
    int which = idx >> 17;
    int r = idx & 131071;
    int n = r >> 10, k = r & 1023;
    const float* src = which ? W012 : W011;
    dst[idx] = (_Float16)src[k * 128 + n];
}

struct WSmall { const float* p[14]; };

__global__ __launch_bounds__(256) void k_wprep_small(WSmall ws, _Float16* __restrict__ dst)
{
    int idx = blockIdx.x * 256 + threadIdx.x;        // 14*16384 = 229376
    int seg = idx >> 14;
    int r = idx & 16383;
    int n = r >> 7, k = r & 127;
    const float* src = ws.p[seg];
    float v = src[k * 128 + n];
    if (seg < 12 && (seg % 3) == 0) v -= src[16384 + k * 128 + n];  // W1diff
    dst[idx] = (_Float16)v;
}

// ---------------- counting sort phase 1: per-dst histogram per mask ----------------
__global__ __launch_bounds__(256) void k_hist(
    const int* __restrict__ attr, const int* __restrict__ edst,
    int* __restrict__ hist)
{
    int e = blockIdx.x * 256 + threadIdx.x;
    int a = attr[e], d = edst[e];
    bool m[6]; eval_masks(a, m);
#pragma unroll
    for (int j = 0; j < 6; ++j)
        if (m[j]) atomicAdd(&hist[j * NNn + d], 1);
}

// ---------------- phase 2: exclusive scan of 32768 bins (one block per mask) ----------------
__global__ __launch_bounds__(256) void k_scan6(
    const int* __restrict__ hist, int* __restrict__ base, int* __restrict__ cnts)
{
    __shared__ int wsum[4];
    __shared__ int carry;
    int j = blockIdx.x;
    int tid = threadIdx.x, lane = tid & 63, wv = tid >> 6;
    if (tid == 0) carry = 0;
    __syncthreads();
    for (int c0 = 0; c0 < NNn; c0 += 256) {
        int v = hist[j * NNn + c0 + tid];
        int x = v;
#pragma unroll
        for (int off = 1; off < 64; off <<= 1) {
            int y = __shfl_up(x, off, 64);
            if (lane >= off) x += y;
        }
        if (lane == 63) wsum[wv] = x;
        __syncthreads();
        int add = carry;
        for (int w = 0; w < wv; ++w) add += wsum[w];
        base[j * NNn + c0 + tid] = add + x - v;
        __syncthreads();
        if (tid == 0) carry += wsum[0] + wsum[1] + wsum[2] + wsum[3];
        __syncthreads();
    }
    if (tid == 0) cnts[j] = carry;
}

// ---------------- phase 3: fill sorted lists ----------------
__global__ __launch_bounds__(256) void k_fill(
    const int* __restrict__ esrc, const int* __restrict__ edst,
    const int* __restrict__ attr, const int* __restrict__ base,
    int* __restrict__ fill, int2* __restrict__ arena)
{
    int e = blockIdx.x * 256 + threadIdx.x;
    int a = attr[e];
    int s = esrc[e], d = edst[e];
    bool m[6]; eval_masks(a, m);
    const int caps[6] = {CAP0, CAP1, CAP2, CAP3, CAP4, CAP5};
    const int offs[6] = {0, CAP0, CAP0+CAP1, CAP0+CAP1+CAP2,
                         CAP0+CAP1+CAP2+CAP3, CAP0+CAP1+CAP2+CAP3+CAP4};
#pragma unroll
    for (int j = 0; j < 6; ++j) {
        if (m[j]) {
            int pos = base[j * NNn + d] + atomicAdd(&fill[j * NNn + d], 1);
            if (pos < caps[j]) arena[offs[j] + pos] = make_int2(s, d);
        }
    }
}

// ---------------- generic GEMM ----------------
// out[M,128] = op(A@BT^T + bias); dualB: also out2 = A@BT2^T.
// dualA (A2!=null): acc += A2@BT2^T (same 128-col output), single out.
__global__ __launch_bounds__(256) void k_gemm(
    const float* __restrict__ A, const _Float16* __restrict__ BT,
    const float* __restrict__ bias, float* __restrict__ out,
    const _Float16* __restrict__ BT2, float* __restrict__ out2,
    const float* __restrict__ A2,
    int M, int K, int do_relu, int do_accum)
{
    __shared__ _Float16 Al[64][40];
    __shared__ _Float16 Bl[128][40];
    __shared__ _Float16 Bl2[128][40];
    const int tid  = threadIdx.x;
    const int wave = tid >> 6;
    const int lane = tid & 63;
    const int m0   = blockIdx.x * 64;

    f32x4 acc[8], acc2[8];
#pragma unroll
    for (int i = 0; i < 8; ++i) { acc[i] = (f32x4){0,0,0,0}; acc2[i] = (f32x4){0,0,0,0}; }

    const int ar = tid >> 2;
    const int ak = (tid & 3) * 8;
    const int fr = wave * 16 + (lane & 15);
    const int fk = (lane >> 4) * 8;

    for (int k0 = 0; k0 < K; k0 += 32) {
        const float* asrc = A + (size_t)(m0 + ar) * K + (k0 + ak);
        float4 a0 = *(const float4*)asrc;
        float4 a1 = *(const float4*)(asrc + 4);
        f16x8 av = { (_Float16)a0.x, (_Float16)a0.y, (_Float16)a0.z, (_Float16)a0.w,
                     (_Float16)a1.x, (_Float16)a1.y, (_Float16)a1.z, (_Float16)a1.w };
        *(f16x8*)&Al[ar][ak] = av;
#pragma unroll
        for (int i = 0; i < 2; ++i) {
            int c = tid + i * 256;
            int n = c >> 2, koff = (c & 3) * 8;
            *(f16x8*)&Bl[n][koff] = *(const f16x8*)(BT + (size_t)n * K + k0 + koff);
            if (out2)
                *(f16x8*)&Bl2[n][koff] = *(const f16x8*)(BT2 + (size_t)n * K + k0 + koff);
        }
        __syncthreads();
        f16x8 af = *(const f16x8*)&Al[fr][fk];
#pragma unroll
        for (int nt = 0; nt < 8; ++nt) {
            f16x8 bf = *(const f16x8*)&Bl[nt * 16 + (lane & 15)][fk];
            acc[nt] = __builtin_amdgcn_mfma_f32_16x16x32_f16(af, bf, acc[nt], 0, 0, 0);
        }
        if (out2) {
#pragma unroll
            for (int nt = 0; nt < 8; ++nt) {
                f16x8 bf = *(const f16x8*)&Bl2[nt * 16 + (lane & 15)][fk];
                acc2[nt] = __builtin_amdgcn_mfma_f32_16x16x32_f16(af, bf, acc2[nt], 0, 0, 0);
            }
        }
        __syncthreads();
    }
    if (A2) {   // dual-A: second GEMM accumulated into acc
        for (int k0 = 0; k0 < K; k0 += 32) {
            const float* asrc = A2 + (size_t)(m0 + ar) * K + (k0 + ak);
            float4 a0 = *(const float4*)asrc;
            float4 a1 = *(const float4*)(asrc + 4);
            f16x8 av = { (_Float16)a0.x, (_Float16)a0.y, (_Float16)a0.z, (_Float16)a0.w,
                         (_Float16)a1.x, (_Float16)a1.y, (_Float16)a1.z, (_Float16)a1.w };
            *(f16x8*)&Al[ar][ak] = av;
#pragma unroll
            for (int i = 0; i < 2; ++i) {
                int c = tid + i * 256;
                int n = c >> 2, koff = (c & 3) * 8;
                *(f16x8*)&Bl[n][koff] = *(const f16x8*)(BT2 + (size_t)n * K + k0 + koff);
            }
            __syncthreads();
            f16x8 af = *(const f16x8*)&Al[fr][fk];
#pragma unroll
            for (int nt = 0; nt < 8; ++nt) {
                f16x8 bf = *(const f16x8*)&Bl[nt * 16 + (lane & 15)][fk];
                acc[nt] = __builtin_amdgcn_mfma_f32_16x16x32_f16(af, bf, acc[nt], 0, 0, 0);
            }
            __syncthreads();
        }
    }

    const int rbase = wave * 16 + (lane >> 4) * 4;
    const int cbase = lane & 15;
#pragma unroll
    for (int nt = 0; nt < 8; ++nt) {
        int col = nt * 16 + cbase;
        float bv = bias ? bias[col] : 0.f;
#pragma unroll
        for (int rr = 0; rr < 4; ++rr) {
            int gr = m0 + rbase + rr;
            size_t o = (size_t)gr * 128 + col;
            float v = acc[nt][rr] + bv;
            if (do_relu) v = fmaxf(v, 0.f);
            if (do_accum) out[o] += v; else out[o] = v;
            if (out2) out2[o] = acc2[nt][rr];
        }
    }
}

// ---------------- edge MLP on dst-sorted list: segmented max, plain stores ----------------
// r = relu(P[d]+V[s]); h = relu(r@W2 + b2); agg[d] = max over group (per-dst)
__global__ __launch_bounds__(256, 3) void k_edge_mlp(
    const float* __restrict__ P, const float* __restrict__ V,
    const _Float16* __restrict__ W2T, const float* __restrict__ b2,
    const int2* __restrict__ list, const int* __restrict__ cntp, int cap,
    float* __restrict__ agg)
{
    __shared__ _Float16 Rl[64][136];        // r tile, then reused for h tile
    __shared__ _Float16 W2l[128][136];
    __shared__ float b2l[128];
    __shared__ int2 eSD[64];
    __shared__ unsigned char gstart[66];
    __shared__ int gdst[64];
    __shared__ int ngrS;

    int cnt = min(*cntp, cap);
    int ntiles = (cnt + 63) >> 6;
    if ((int)blockIdx.x >= ntiles) return;

    const int tid  = threadIdx.x;
    const int wave = tid >> 6;
    const int lane = tid & 63;

    // stage W2^T once per block
#pragma unroll
    for (int i = 0; i < 8; ++i) {
        int c = tid + i * 256;
        int n = c >> 4, koff = (c & 15) * 8;
        *(f16x8*)&W2l[n][koff] = *(const f16x8*)(W2T + n * 128 + koff);
    }
    if (tid < 128) b2l[tid] = b2[tid];

    const int col   = tid & 127;
    const int half  = tid >> 7;
    const int frow  = wave * 16 + (lane & 15);
    const int fq    = (lane >> 4) * 8;
    const int rbase = wave * 16 + (lane >> 4) * 4;
    const int cbase = lane & 15;

    for (int t = blockIdx.x; t < ntiles; t += gridDim.x) {
        __syncthreads();                       // LDS reuse guard
        if (tid < 64) {
            int e = t * 64 + tid;
            eSD[tid] = (e < cnt) ? list[e] : make_int2(0, -1);
        }
        __syncthreads();
        // group boundaries (wave 0 only; list is dst-sorted so groups are runs)
        if (tid < 64) {
            int d = eSD[tid].y;
            bool flag = (tid == 0) || (d != eSD[tid - 1].y);
            unsigned long long bm = __ballot(flag);
            int rank = (int)__popcll(bm & ((1ull << tid) - 1ull));
            if (flag) { gstart[rank] = (unsigned char)tid; gdst[rank] = d; }
            if (tid == 0) {
                int ng = (int)__popcll(bm);
                ngrS = ng;
                gstart[ng] = 64;
            }
        }
        // build r tile
#pragma unroll
        for (int it = 0; it < 32; ++it) {
            int i = it * 2 + half;
            float r = 0.f;
            int2 sd = eSD[i];
            if (sd.y >= 0)
                r = fmaxf(P[(size_t)sd.y * 128 + col] + V[(size_t)sd.x * 128 + col], 0.f);
            Rl[i][col] = (_Float16)r;
        }
        __syncthreads();

        f32x4 acc[8];
#pragma unroll
        for (int i = 0; i < 8; ++i) acc[i] = (f32x4){0,0,0,0};
#pragma unroll
        for (int t4 = 0; t4 < 4; ++t4) {
            f16x8 af = *(const f16x8*)&Rl[frow][t4 * 32 + fq];
#pragma unroll
            for (int nt = 0; nt < 8; ++nt) {
                f16x8 bf = *(const f16x8*)&W2l[nt * 16 + (lane & 15)][t4 * 32 + fq];
                acc[nt] = __builtin_amdgcn_mfma_f32_16x16x32_f16(af, bf, acc[nt], 0, 0, 0);
            }
        }
        __syncthreads();                       // all MFMA reads of Rl done
        // write h = relu(acc + b2) back into Rl (wave w owns rows 16w..16w+15)
#pragma unroll
        for (int nt = 0; nt < 8; ++nt) {
            int c2 = nt * 16 + cbase;
            float bv = b2l[c2];
#pragma unroll
            for (int rr = 0; rr < 4; ++rr)
                Rl[rbase + rr][c2] = (_Float16)fmaxf(acc[nt][rr] + bv, 0.f);
        }
        __syncthreads();
        // segmented max per dst-group; plain store for interior groups
        int ng = ngrS;
        for (int g = half; g < ng; g += 2) {
            int s = gstart[g], e = gstart[g + 1];
            int d = gdst[g];
            if (d < 0) continue;
            float m = 0.f;
            for (int i = s; i < e; ++i)
                m = fmaxf(m, (float)Rl[i][col]);
            size_t o = (size_t)d * 128 + col;
            if (s == 0 || e == 64)
                atomicMax((unsigned int*)&agg[o], __float_as_uint(m));
            else
                agg[o] = m;
        }
    }
}

// ---------------- CSR gather-reduce kernels (no atomics) ----------------
// sage mean: S[d] = (sum over in-edges of H[src]) / cnt
__global__ __launch_bounds__(256) void k_csr_mean(
    const float* __restrict__ H, const int2* __restrict__ list,
    const int* __restrict__ base, const int* __restrict__ cntarr, int cap,
    float* __restrict__ S)
{
    int col = threadIdx.x & 127;
    int sub = threadIdx.x >> 7;
    for (int d = blockIdx.x * 2 + sub; d < NNn; d += gridDim.x * 2) {
        int c = cntarr[d];
        if (c == 0) continue;
        int b = base[d];
        if (b >= cap) continue;
        int end = min(b + c, cap);
        float s = 0.f;
        for (int i = b; i < end; ++i)
            s += H[(size_t)list[i].x * 128 + col];
        S[(size_t)d * 128 + col] = s / (float)c;
    }
}

// vpa: out[d] = relu(x[d] + max over in-edges of x[src]) (empty -> 0, buffer pre-zeroed)
__global__ __launch_bounds__(256) void k_csr_vpa(
    const float* __restrict__ X, const int2* __restrict__ list,
    const int* __restrict__ base, const int* __restrict__ cntarr, int cap,
    float* __restrict__ S)
{
    int col = threadIdx.x & 127;
    int sub = threadIdx.x >> 7;
    for (int d = blockIdx.x * 2 + sub; d < NNn; d += gridDim.x * 2) {
        int c = cntarr[d];
        if (c == 0) continue;
        int b = base[d];
        if (b >= cap) continue;
        int end = min(b + c, cap);
        float mx = -3.0e38f;
        for (int i = b; i < end; ++i)
            mx = fmaxf(mx, X[(size_t)list[i].x * 128 + col]);
        float v = X[(size_t)d * 128 + col] + mx;
        S[(size_t)d * 128 + col] = fmaxf(v, 0.f);
    }
}

// acv: out[d] = relu(sum(ares[s]*x[s]) + cnt*x[d])
__global__ __launch_bounds__(256) void k_csr_acv(
    const float* __restrict__ X, const float* __restrict__ ares,
    const int2* __restrict__ list,
    const int* __restrict__ base, const int* __restrict__ cntarr, int cap,
    float* __restrict__ S)
{
    int col = threadIdx.x & 127;
    int sub = threadIdx.x >> 7;
    for (int d = blockIdx.x * 2 + sub; d < NNn; d += gridDim.x * 2) {
        int c = cntarr[d];
        if (c == 0) continue;
        int b = base[d];
        if (b >= cap) continue;
        int end = min(b + c, cap);
        float s = 0.f;
        for (int i = b; i < end; ++i) {
            int sr = list[i].x;
            s += ares[sr] * X[(size_t)sr * 128 + col];
        }
        float v = s + (float)c * X[(size_t)d * 128 + col];
        S[(size_t)d * 128 + col] = fmaxf(v, 0.f);
    }
}

// ---------------- fc: a_res = a @ fc_W + fc_b ----------------
__global__ __launch_bounds__(256) void k_fc(
    const float* __restrict__ A, const float* __restrict__ W,
    const float* __restrict__ b, float* __restrict__ ares)
{
    int node = blockIdx.x * 4 + (threadIdx.x >> 6);
    int lane = threadIdx.x & 63;
    const float* row = A + (size_t)node * 128;
    float v = row[lane] * W[lane] + row[lane + 64] * W[lane + 64];
#pragma unroll
    for (int off = 32; off > 0; off >>= 1) v += __shfl_down(v, off, 64);
    if (lane == 0) ares[node] = v + b[0];
}

__global__ __launch_bounds__(256) void k_gather(
    const float* __restrict__ xo, const int* __restrict__ spk, float* __restrict__ out)
{
    int gid = blockIdx.x * 256 + threadIdx.x;
    int cc = gid & 127, t = (gid >> 7) & 127, g = gid >> 14;
    int node = g * (spk[0] * TT) + t;
    out[gid] = xo[(size_t)node * 128 + cc];
}

extern "C" void kernel_launch(void* const* d_in, const int* in_sizes, int n_in,
                              void* d_out, int out_size, void* d_ws, size_t ws_size,
                              hipStream_t stream)
{
    (void)in_sizes; (void)n_in; (void)ws_size;
    const float* xv   = (const float*)d_in[0];
    const float* xa   = (const float*)d_in[1];
    const float* W011 = (const float*)d_in[2];
    const float* b011 = (const float*)d_in[3];
    const float* W012 = (const float*)d_in[4];
    const float* b012 = (const float*)d_in[5];
    const float* ecW1[4] = {(const float*)d_in[6],  (const float*)d_in[10],
                            (const float*)d_in[14], (const float*)d_in[18]};
    const float* ecb1[4] = {(const float*)d_in[7],  (const float*)d_in[11],
                            (const float*)d_in[15], (const float*)d_in[19]};
    const float* ecW2[4] = {(const float*)d_in[8],  (const float*)d_in[12],
                            (const float*)d_in[16], (const float*)d_in[20]};
    const float* ecb2[4] = {(const float*)d_in[9],  (const float*)d_in[13],
                            (const float*)d_in[17], (const float*)d_in[21]};
    const float* sageWl = (const float*)d_in[22];
    const float* sagebl = (const float*)d_in[23];
    const float* sageWr = (const float*)d_in[24];
    const float* fcW    = (const float*)d_in[25];
    const float* fcb    = (const float*)d_in[26];
    const int*   esrc   = (const int*)d_in[27];
    const int*   edst   = esrc + EEe;
    const int*   attr   = (const int*)d_in[28];
    const int*   spk    = (const int*)d_in[29];
    float* out = (float*)d_out;

    const size_t NC = (size_t)NNn * CCc;
    float* ws   = (float*)d_ws;
    float* X    = ws;
    float* S1   = ws + 1 * NC;    // vpa out / sage mean (zeroed together with AH)
    float* AH   = ws + 2 * NC;    // edge-mlp aggregate
    float* P    = ws + 3 * NC;
    float* V    = ws + 4 * NC;
    float* XV2  = ws + 5 * NC;
    float* XO   = ws + 6 * NC;
    float* ARES = ws + 7 * NC;               // 32768
    int*   cnts = (int*)(ARES + NNn);        // 16 ints
    int*   hist = cnts + 16;                 // 6*32768
    int*   fill = hist + 6 * NNn;            // 6*32768
    int*   base = fill + 6 * NNn;            // 6*32768
    int2*  arena = (int2*)(base + 6 * NNn);
    _Float16* WT = (_Float16*)(arena + ARENA_TOTAL);

    const int offs[6] = {0, CAP0, CAP0+CAP1, CAP0+CAP1+CAP2,
                         CAP0+CAP1+CAP2+CAP3, CAP0+CAP1+CAP2+CAP3+CAP4};
    const int caps[6] = {CAP0, CAP1, CAP2, CAP3, CAP4, CAP5};

    const _Float16* W011T = WT;
    const _Float16* W012T = WT + 131072;
    const _Float16* WTs   = WT + 262144;
    const _Float16* WlT   = WTs + 12 * 16384;
    const _Float16* WrT   = WTs + 13 * 16384;

    const int GN  = NNn / 64;          // 512
    const int GNC = (int)(NC / 1024);  // 4096

    // ---- weight prep + counting-sort CSR build ----
    k_wprep_big<<<1024, 256, 0, stream>>>(W011, W012, WT);
    WSmall wsm;
    for (int i = 0; i < 4; ++i) {
        wsm.p[3*i + 0] = ecW1[i];
        wsm.p[3*i + 1] = ecW1[i] + 16384;
        wsm.p[3*i + 2] = ecW2[i];
    }
    wsm.p[12] = sageWl; wsm.p[13] = sageWr;
    k_wprep_small<<<896, 256, 0, stream>>>(wsm, (_Float16*)WTs);
    k_zero<<<(2 * 6 * NNn) / 1024, 256, 0, stream>>>((float*)hist);  // hist + fill
    k_hist<<<EEe / 256, 256, 0, stream>>>(attr, edst, hist);
    k_scan6<<<6, 256, 0, stream>>>(hist, base, cnts);
    k_fill<<<EEe / 256, 256, 0, stream>>>(esrc, edst, attr, base, fill, arena);

    // ---- x = [xv @ W011 + b011 ; xa @ W012 + b012] ----
    k_gemm<<<NVv * TT / 64, 256, 0, stream>>>(xv, W011T, b011, X,
                                              nullptr, nullptr, nullptr, NVv * TT, FDd, 0, 0);
    k_gemm<<<NAa * TT / 64, 256, 0, stream>>>(xa, W012T, b012,
                                              X + (size_t)NVv * TT * CCc,
                                              nullptr, nullptr, nullptr, NAa * TT, FDd, 0, 0);
    // ---- xa_g = relu(x[d] + max in-edge x[s]) (mask 0) ----
    k_zero<<<2 * GNC, 256, 0, stream>>>(S1);    // S1 + AH
    k_csr_vpa<<<2048, 256, 0, stream>>>(X, arena + offs[0], base + 0 * NNn,
                                        hist + 0 * NNn, caps[0], S1);
    // ---- EdgeConv A (mask 1) ----
    k_gemm<<<GN, 256, 0, stream>>>(S1, WTs, ecb1[0], P,
                                   WTs + 16384, V, nullptr, NNn, CCc, 0, 0);
    k_edge_mlp<<<1024, 256, 0, stream>>>(P, V, WTs + 2 * 16384, ecb2[0],
                                         arena + offs[1], cnts + 1, caps[1], AH);
    k_fc<<<NNn / 4, 256, 0, stream>>>(AH, fcW, fcb, ARES);
    // ---- xv2 (mask 2) ----
    k_zero<<<2 * GNC, 256, 0, stream>>>(XV2);   // XV2 + XO
    k_csr_acv<<<2048, 256, 0, stream>>>(X, ARES, arena + offs[2], base + 2 * NNn,
                                        hist + 2 * NNn, caps[2], XV2);
    // ---- three branches ----
    for (int b = 0; b < 3; ++b) {
        int j = 3 + b;
        const _Float16* Wd = WTs + (3 * (b + 1)) * 16384;
        k_gemm<<<GN, 256, 0, stream>>>(XV2, Wd, ecb1[b + 1], P,
                                       Wd + 16384, V, nullptr, NNn, CCc, 0, 0);
        k_zero<<<2 * GNC, 256, 0, stream>>>(S1);             // S1 + AH
        k_edge_mlp<<<1024, 256, 0, stream>>>(P, V, Wd + 2 * 16384, ecb2[b + 1],
                                             arena + offs[j], cnts + j, caps[j], AH);
        k_csr_mean<<<2048, 256, 0, stream>>>(AH, arena + offs[j], base + j * NNn,
                                             hist + j * NNn, caps[j], S1);
        // xo += relu(S1@Wl + AH@Wr + bl)   (dual-A fused)
        k_gemm<<<GN, 256, 0, stream>>>(S1, WlT, sagebl, XO,
                                       WrT, nullptr, AH, NNn, CCc, 1, 1);
    }
    k_gather<<<out_size / 256, 256, 0, stream>>>(XO, spk, out);
}

// Round 5
// 794.565 us; speedup vs baseline: 1.6730x; 1.1148x over previous
//
#include <hip/hip_runtime.h>
#include <cstdint>
#include <cstddef>

#define NVv 192
#define NAa 64
#define TT 128
#define FDd 1024
#define CCc 128
#define EEe 262144
#define NNn 32768

typedef _Float16 f16x8 __attribute__((ext_vector_type(8)));
typedef float f32x4 __attribute__((ext_vector_type(4)));

// list arena capacities/offsets (int2 units): vpa, aud, acv, m1, m2, m3
#define CAP0 65536
#define CAP1 65536
#define CAP2 65536
#define CAP3 98304
#define CAP4 98304
#define CAP5 147456
#define ARENA_TOTAL (CAP0+CAP1+CAP2+CAP3+CAP4+CAP5)   // 540672

__device__ __forceinline__ void eval_masks(int a, bool m[6]) {
    m[0] = (a == -3); m[1] = (a == -2); m[2] = (a == 3);
    m[3] = (a >= 0) & (a <= 1);
    m[4] = (a >= -1) & (a <= 0);
    m[5] = (a >= -1) & (a <= 1);
}

// ---------------- zero fill (1024 floats / block) ----------------
__global__ __launch_bounds__(256) void k_zero(float* __restrict__ p) {
    size_t i = (size_t)blockIdx.x * 1024 + (size_t)threadIdx.x * 4;
    *(float4*)(p + i) = make_float4(0.f, 0.f, 0.f, 0.f);
}

// ---------------- weight prep: f32 [K][128] -> f16 transposed [128][K] ----------------
__global__ __launch_bounds__(256) void k_wprep_big(
    const float* __restrict__ W011, const float* __restrict__ W012,
    _Float16* __restrict__ dst)
{
    int idx = blockIdx.x * 256 + threadIdx.x;        // 262144
    int which = idx >> 17;
    int r = idx & 131071;
    int n = r >> 10, k = r & 1023;
    const float* src = which ? W012 : W011;
    dst[idx] = (_Float16)src[k * 128 + n];
}

struct WSmall { const float* p[14]; };

__global__ __launch_bounds__(256) void k_wprep_small(WSmall ws, _Float16* __restrict__ dst)
{
    int idx = blockIdx.x * 256 + threadIdx.x;        // 14*16384 = 229376
    int seg = idx >> 14;
    int r = idx & 16383;
    int n = r >> 7, k = r & 127;
    const float* src = ws.p[seg];
    float v = src[k * 128 + n];
    if (seg < 12 && (seg % 3) == 0) v -= src[16384 + k * 128 + n];  // W1diff
    dst[idx] = (_Float16)v;
}

// ---------------- counting sort phase 1: per-dst histogram per mask ----------------
__global__ __launch_bounds__(256) void k_hist(
    const int* __restrict__ attr, const int* __restrict__ edst,
    int* __restrict__ hist)
{
    int e = blockIdx.x * 256 + threadIdx.x;
    int a = attr[e], d = edst[e];
    bool m[6]; eval_masks(a, m);
#pragma unroll
    for (int j = 0; j < 6; ++j)
        if (m[j]) atomicAdd(&hist[j * NNn + d], 1);
}

// ---------------- hierarchical exclusive scan (scan-then-propagate) ----------------
// phase A: 768 blocks (6 masks x 128 chunks of 256 bins): local exclusive scan + block total
__global__ __launch_bounds__(256) void k_scan_a(
    const int* __restrict__ hist, int* __restrict__ base, int* __restrict__ bsum)
{
    __shared__ int wsum[4];
    int bid = blockIdx.x;               // 0..767
    int idx = bid * 256 + threadIdx.x;  // = j*NNn + chunk*256 + tid (contiguous)
    int tid = threadIdx.x, lane = tid & 63, wv = tid >> 6;
    int v = hist[idx];
    int x = v;
#pragma unroll
    for (int off = 1; off < 64; off <<= 1) {
        int y = __shfl_up(x, off, 64);
        if (lane >= off) x += y;
    }
    if (lane == 63) wsum[wv] = x;
    __syncthreads();
    int add = 0;
    for (int w = 0; w < wv; ++w) add += wsum[w];
    base[idx] = add + x - v;            // exclusive within block
    if (tid == 255) bsum[bid] = add + x;
}

// phase B: one block, wave j scans the 128 block-totals of mask j
__global__ __launch_bounds__(384) void k_scan_b(int* __restrict__ bsum, int* __restrict__ cnts)
{
    int wv = threadIdx.x >> 6;        // 0..5 = mask
    int lane = threadIdx.x & 63;
    int run = 0;
#pragma unroll
    for (int c0 = 0; c0 < 128; c0 += 64) {
        int v = bsum[wv * 128 + c0 + lane];
        int x = v;
#pragma unroll
        for (int off = 1; off < 64; off <<= 1) {
            int y = __shfl_up(x, off, 64);
            if (lane >= off) x += y;
        }
        bsum[wv * 128 + c0 + lane] = run + (x - v);
        run += __shfl(x, 63, 64);
    }
    if (lane == 0) cnts[wv] = run;
}

// phase C: propagate block offsets
__global__ __launch_bounds__(256) void k_scan_c(int* __restrict__ base, const int* __restrict__ bsum)
{
    int bid = blockIdx.x;
    base[bid * 256 + threadIdx.x] += bsum[bid];
}

// ---------------- phase 3: fill sorted lists ----------------
__global__ __launch_bounds__(256) void k_fill(
    const int* __restrict__ esrc, const int* __restrict__ edst,
    const int* __restrict__ attr, const int* __restrict__ base,
    int* __restrict__ fill, int2* __restrict__ arena)
{
    int e = blockIdx.x * 256 + threadIdx.x;
    int a = attr[e];
    int s = esrc[e], d = edst[e];
    bool m[6]; eval_masks(a, m);
    const int caps[6] = {CAP0, CAP1, CAP2, CAP3, CAP4, CAP5};
    const int offs[6] = {0, CAP0, CAP0+CAP1, CAP0+CAP1+CAP2,
                         CAP0+CAP1+CAP2+CAP3, CAP0+CAP1+CAP2+CAP3+CAP4};
#pragma unroll
    for (int j = 0; j < 6; ++j) {
        if (m[j]) {
            int pos = base[j * NNn + d] + atomicAdd(&fill[j * NNn + d], 1);
            if (pos < caps[j]) arena[offs[j] + pos] = make_int2(s, d);
        }
    }
}

// ---------------- generic GEMM ----------------
// out[M,128] = op(A@BT^T + bias); dualB: also out2 = A@BT2^T.
// dualA (A2!=null): acc += A2@BT2^T (same 128-col output), single out.
__global__ __launch_bounds__(256) void k_gemm(
    const float* __restrict__ A, const _Float16* __restrict__ BT,
    const float* __restrict__ bias, float* __restrict__ out,
    const _Float16* __restrict__ BT2, float* __restrict__ out2,
    const float* __restrict__ A2,
    int M, int K, int do_relu, int do_accum)
{
    __shared__ _Float16 Al[64][40];
    __shared__ _Float16 Bl[128][40];
    __shared__ _Float16 Bl2[128][40];
    const int tid  = threadIdx.x;
    const int wave = tid >> 6;
    const int lane = tid & 63;
    const int m0   = blockIdx.x * 64;

    f32x4 acc[8], acc2[8];
#pragma unroll
    for (int i = 0; i < 8; ++i) { acc[i] = (f32x4){0,0,0,0}; acc2[i] = (f32x4){0,0,0,0}; }

    const int ar = tid >> 2;
    const int ak = (tid & 3) * 8;
    const int fr = wave * 16 + (lane & 15);
    const int fk = (lane >> 4) * 8;

    for (int k0 = 0; k0 < K; k0 += 32) {
        const float* asrc = A + (size_t)(m0 + ar) * K + (k0 + ak);
        float4 a0 = *(const float4*)asrc;
        float4 a1 = *(const float4*)(asrc + 4);
        f16x8 av = { (_Float16)a0.x, (_Float16)a0.y, (_Float16)a0.z, (_Float16)a0.w,
                     (_Float16)a1.x, (_Float16)a1.y, (_Float16)a1.z, (_Float16)a1.w };
        *(f16x8*)&Al[ar][ak] = av;
#pragma unroll
        for (int i = 0; i < 2; ++i) {
            int c = tid + i * 256;
            int n = c >> 2, koff = (c & 3) * 8;
            *(f16x8*)&Bl[n][koff] = *(const f16x8*)(BT + (size_t)n * K + k0 + koff);
            if (out2)
                *(f16x8*)&Bl2[n][koff] = *(const f16x8*)(BT2 + (size_t)n * K + k0 + koff);
        }
        __syncthreads();
        f16x8 af = *(const f16x8*)&Al[fr][fk];
#pragma unroll
        for (int nt = 0; nt < 8; ++nt) {
            f16x8 bf = *(const f16x8*)&Bl[nt * 16 + (lane & 15)][fk];
            acc[nt] = __builtin_amdgcn_mfma_f32_16x16x32_f16(af, bf, acc[nt], 0, 0, 0);
        }
        if (out2) {
#pragma unroll
            for (int nt = 0; nt < 8; ++nt) {
                f16x8 bf = *(const f16x8*)&Bl2[nt * 16 + (lane & 15)][fk];
                acc2[nt] = __builtin_amdgcn_mfma_f32_16x16x32_f16(af, bf, acc2[nt], 0, 0, 0);
            }
        }
        __syncthreads();
    }
    if (A2) {   // dual-A: second GEMM accumulated into acc
        for (int k0 = 0; k0 < K; k0 += 32) {
            const float* asrc = A2 + (size_t)(m0 + ar) * K + (k0 + ak);
            float4 a0 = *(const float4*)asrc;
            float4 a1 = *(const float4*)(asrc + 4);
            f16x8 av = { (_Float16)a0.x, (_Float16)a0.y, (_Float16)a0.z, (_Float16)a0.w,
                         (_Float16)a1.x, (_Float16)a1.y, (_Float16)a1.z, (_Float16)a1.w };
            *(f16x8*)&Al[ar][ak] = av;
#pragma unroll
            for (int i = 0; i < 2; ++i) {
                int c = tid + i * 256;
                int n = c >> 2, koff = (c & 3) * 8;
                *(f16x8*)&Bl[n][koff] = *(const f16x8*)(BT2 + (size_t)n * K + k0 + koff);
            }
            __syncthreads();
            f16x8 af = *(const f16x8*)&Al[fr][fk];
#pragma unroll
            for (int nt = 0; nt < 8; ++nt) {
                f16x8 bf = *(const f16x8*)&Bl[nt * 16 + (lane & 15)][fk];
                acc[nt] = __builtin_amdgcn_mfma_f32_16x16x32_f16(af, bf, acc[nt], 0, 0, 0);
            }
            __syncthreads();
        }
    }

    const int rbase = wave * 16 + (lane >> 4) * 4;
    const int cbase = lane & 15;
#pragma unroll
    for (int nt = 0; nt < 8; ++nt) {
        int col = nt * 16 + cbase;
        float bv = bias ? bias[col] : 0.f;
#pragma unroll
        for (int rr = 0; rr < 4; ++rr) {
            int gr = m0 + rbase + rr;
            size_t o = (size_t)gr * 128 + col;
            float v = acc[nt][rr] + bv;
            if (do_relu) v = fmaxf(v, 0.f);
            if (do_accum) out[o] += v; else out[o] = v;
            if (out2) out2[o] = acc2[nt][rr];
        }
    }
}

// ---------------- edge MLP on dst-sorted list: segmented max, plain stores ----------------
// r = relu(P[d]+V[s]); h = relu(r@W2 + b2); agg[d] = max over group (per-dst)
__global__ __launch_bounds__(256, 3) void k_edge_mlp(
    const float* __restrict__ P, const float* __restrict__ V,
    const _Float16* __restrict__ W2T, const float* __restrict__ b2,
    const int2* __restrict__ list, const int* __restrict__ cntp, int cap,
    float* __restrict__ agg)
{
    __shared__ _Float16 Rl[64][136];        // r tile, then reused for h tile
    __shared__ _Float16 W2l[128][136];
    __shared__ float b2l[128];
    __shared__ int2 eSD[64];
    __shared__ unsigned char gstart[66];
    __shared__ int gdst[64];
    __shared__ int ngrS;

    int cnt = min(*cntp, cap);
    int ntiles = (cnt + 63) >> 6;
    if ((int)blockIdx.x >= ntiles) return;

    const int tid  = threadIdx.x;
    const int wave = tid >> 6;
    const int lane = tid & 63;

    // stage W2^T once per block
#pragma unroll
    for (int i = 0; i < 8; ++i) {
        int c = tid + i * 256;
        int n = c >> 4, koff = (c & 15) * 8;
        *(f16x8*)&W2l[n][koff] = *(const f16x8*)(W2T + n * 128 + koff);
    }
    if (tid < 128) b2l[tid] = b2[tid];

    const int col   = tid & 127;
    const int half  = tid >> 7;
    const int frow  = wave * 16 + (lane & 15);
    const int fq    = (lane >> 4) * 8;
    const int rbase = wave * 16 + (lane >> 4) * 4;
    const int cbase = lane & 15;

    for (int t = blockIdx.x; t < ntiles; t += gridDim.x) {
        __syncthreads();                       // LDS reuse guard
        if (tid < 64) {
            int e = t * 64 + tid;
            eSD[tid] = (e < cnt) ? list[e] : make_int2(0, -1);
        }
        __syncthreads();
        // group boundaries (wave 0 only; list is dst-sorted so groups are runs)
        if (tid < 64) {
            int d = eSD[tid].y;
            bool flag = (tid == 0) || (d != eSD[tid - 1].y);
            unsigned long long bm = __ballot(flag);
            int rank = (int)__popcll(bm & ((1ull << tid) - 1ull));
            if (flag) { gstart[rank] = (unsigned char)tid; gdst[rank] = d; }
            if (tid == 0) {
                int ng = (int)__popcll(bm);
                ngrS = ng;
                gstart[ng] = 64;
            }
        }
        // build r tile
#pragma unroll
        for (int it = 0; it < 32; ++it) {
            int i = it * 2 + half;
            float r = 0.f;
            int2 sd = eSD[i];
            if (sd.y >= 0)
                r = fmaxf(P[(size_t)sd.y * 128 + col] + V[(size_t)sd.x * 128 + col], 0.f);
            Rl[i][col] = (_Float16)r;
        }
        __syncthreads();

        f32x4 acc[8];
#pragma unroll
        for (int i = 0; i < 8; ++i) acc[i] = (f32x4){0,0,0,0};
#pragma unroll
        for (int t4 = 0; t4 < 4; ++t4) {
            f16x8 af = *(const f16x8*)&Rl[frow][t4 * 32 + fq];
#pragma unroll
            for (int nt = 0; nt < 8; ++nt) {
                f16x8 bf = *(const f16x8*)&W2l[nt * 16 + (lane & 15)][t4 * 32 + fq];
                acc[nt] = __builtin_amdgcn_mfma_f32_16x16x32_f16(af, bf, acc[nt], 0, 0, 0);
            }
        }
        __syncthreads();                       // all MFMA reads of Rl done
        // write h = relu(acc + b2) back into Rl (wave w owns rows 16w..16w+15)
#pragma unroll
        for (int nt = 0; nt < 8; ++nt) {
            int c2 = nt * 16 + cbase;
            float bv = b2l[c2];
#pragma unroll
            for (int rr = 0; rr < 4; ++rr)
                Rl[rbase + rr][c2] = (_Float16)fmaxf(acc[nt][rr] + bv, 0.f);
        }
        __syncthreads();
        // segmented max per dst-group; plain store for interior groups
        int ng = ngrS;
        for (int g = half; g < ng; g += 2) {
            int s = gstart[g], e = gstart[g + 1];
            int d = gdst[g];
            if (d < 0) continue;
            float m = 0.f;
            for (int i = s; i < e; ++i)
                m = fmaxf(m, (float)Rl[i][col]);
            size_t o = (size_t)d * 128 + col;
            if (s == 0 || e == 64)
                atomicMax((unsigned int*)&agg[o], __float_as_uint(m));
            else
                agg[o] = m;
        }
    }
}

// ---------------- CSR gather-reduce kernels (no atomics; write 0 for empty nodes) ----------------
// sage mean: S[d] = (sum over in-edges of H[src]) / cnt   (0 if no edges)
__global__ __launch_bounds__(256) void k_csr_mean(
    const float* __restrict__ H, const int2* __restrict__ list,
    const int* __restrict__ base, const int* __restrict__ cntarr, int cap,
    float* __restrict__ S)
{
    int col = threadIdx.x & 127;
    int sub = threadIdx.x >> 7;
    for (int d = blockIdx.x * 2 + sub; d < NNn; d += gridDim.x * 2) {
        int c = cntarr[d];
        float v = 0.f;
        if (c > 0) {
            int b = base[d];
            int end = min(b + c, cap);
            float s = 0.f;
            for (int i = b; i < end; ++i)
                s += H[(size_t)list[i].x * 128 + col];
            v = s / (float)c;
        }
        S[(size_t)d * 128 + col] = v;
    }
}

// vpa: out[d] = relu(x[d] + max over in-edges of x[src]) (empty -> 0)
__global__ __launch_bounds__(256) void k_csr_vpa(
    const float* __restrict__ X, const int2* __restrict__ list,
    const int* __restrict__ base, const int* __restrict__ cntarr, int cap,
    float* __restrict__ S)
{
    int col = threadIdx.x & 127;
    int sub = threadIdx.x >> 7;
    for (int d = blockIdx.x * 2 + sub; d < NNn; d += gridDim.x * 2) {
        int c = cntarr[d];
        float v = 0.f;
        if (c > 0) {
            int b = base[d];
            int end = min(b + c, cap);
            float mx = -3.0e38f;
            for (int i = b; i < end; ++i)
                mx = fmaxf(mx, X[(size_t)list[i].x * 128 + col]);
            v = fmaxf(X[(size_t)d * 128 + col] + mx, 0.f);
        }
        S[(size_t)d * 128 + col] = v;
    }
}

// acv: out[d] = relu(sum(ares[s]*x[s]) + cnt*x[d]) (empty -> 0)
__global__ __launch_bounds__(256) void k_csr_acv(
    const float* __restrict__ X, const float* __restrict__ ares,
    const int2* __restrict__ list,
    const int* __restrict__ base, const int* __restrict__ cntarr, int cap,
    float* __restrict__ S)
{
    int col = threadIdx.x & 127;
    int sub = threadIdx.x >> 7;
    for (int d = blockIdx.x * 2 + sub; d < NNn; d += gridDim.x * 2) {
        int c = cntarr[d];
        float v = 0.f;
        if (c > 0) {
            int b = base[d];
            int end = min(b + c, cap);
            float s = 0.f;
            for (int i = b; i < end; ++i) {
                int sr = list[i].x;
                s += ares[sr] * X[(size_t)sr * 128 + col];
            }
            v = fmaxf(s + (float)c * X[(size_t)d * 128 + col], 0.f);
        }
        S[(size_t)d * 128 + col] = v;
    }
}

// ---------------- fc: a_res = a @ fc_W + fc_b ----------------
__global__ __launch_bounds__(256) void k_fc(
    const float* __restrict__ A, const float* __restrict__ W,
    const float* __restrict__ b, float* __restrict__ ares)
{
    int node = blockIdx.x * 4 + (threadIdx.x >> 6);
    int lane = threadIdx.x & 63;
    const float* row = A + (size_t)node * 128;
    float v = row[lane] * W[lane] + row[lane + 64] * W[lane + 64];
#pragma unroll
    for (int off = 32; off > 0; off >>= 1) v += __shfl_down(v, off, 64);
    if (lane == 0) ares[node] = v + b[0];
}

__global__ __launch_bounds__(256) void k_gather(
    const float* __restrict__ xo, const int* __restrict__ spk, float* __restrict__ out)
{
    int gid = blockIdx.x * 256 + threadIdx.x;
    int cc = gid & 127, t = (gid >> 7) & 127, g = gid >> 14;
    int node = g * (spk[0] * TT) + t;
    out[gid] = xo[(size_t)node * 128 + cc];
}

extern "C" void kernel_launch(void* const* d_in, const int* in_sizes, int n_in,
                              void* d_out, int out_size, void* d_ws, size_t ws_size,
                              hipStream_t stream)
{
    (void)in_sizes; (void)n_in; (void)ws_size;
    const float* xv   = (const float*)d_in[0];
    const float* xa   = (const float*)d_in[1];
    const float* W011 = (const float*)d_in[2];
    const float* b011 = (const float*)d_in[3];
    const float* W012 = (const float*)d_in[4];
    const float* b012 = (const float*)d_in[5];
    const float* ecW1[4] = {(const float*)d_in[6],  (const float*)d_in[10],
                            (const float*)d_in[14], (const float*)d_in[18]};
    const float* ecb1[4] = {(const float*)d_in[7],  (const float*)d_in[11],
                            (const float*)d_in[15], (const float*)d_in[19]};
    const float* ecW2[4] = {(const float*)d_in[8],  (const float*)d_in[12],
                            (const float*)d_in[16], (const float*)d_in[20]};
    const float* ecb2[4] = {(const float*)d_in[9],  (const float*)d_in[13],
                            (const float*)d_in[17], (const float*)d_in[21]};
    const float* sageWl = (const float*)d_in[22];
    const float* sagebl = (const float*)d_in[23];
    const float* sageWr = (const float*)d_in[24];
    const float* fcW    = (const float*)d_in[25];
    const float* fcb    = (const float*)d_in[26];
    const int*   esrc   = (const int*)d_in[27];
    const int*   edst   = esrc + EEe;
    const int*   attr   = (const int*)d_in[28];
    const int*   spk    = (const int*)d_in[29];
    float* out = (float*)d_out;

    const size_t NC = (size_t)NNn * CCc;
    float* ws   = (float*)d_ws;
    float* X    = ws;
    float* S1   = ws + 1 * NC;    // vpa out / sage mean
    float* AH   = ws + 2 * NC;    // edge-mlp aggregate (needs zeroing)
    float* P    = ws + 3 * NC;
    float* V    = ws + 4 * NC;
    float* XV2  = ws + 5 * NC;
    float* XO   = ws + 6 * NC;    // accumulator (needs zeroing)
    float* ARES = ws + 7 * NC;               // 32768
    int*   cnts = (int*)(ARES + NNn);        // 16 ints
    int*   bsum = cnts + 16;                 // 768 block sums
    int*   hist = bsum + 768;                // 6*32768
    int*   fill = hist + 6 * NNn;            // 6*32768
    int*   base = fill + 6 * NNn;            // 6*32768
    int2*  arena = (int2*)(base + 6 * NNn);
    _Float16* WT = (_Float16*)(arena + ARENA_TOTAL);

    const int offs[6] = {0, CAP0, CAP0+CAP1, CAP0+CAP1+CAP2,
                         CAP0+CAP1+CAP2+CAP3, CAP0+CAP1+CAP2+CAP3+CAP4};
    const int caps[6] = {CAP0, CAP1, CAP2, CAP3, CAP4, CAP5};

    const _Float16* W011T = WT;
    const _Float16* W012T = WT + 131072;
    const _Float16* WTs   = WT + 262144;
    const _Float16* WlT   = WTs + 12 * 16384;
    const _Float16* WrT   = WTs + 13 * 16384;

    const int GN  = NNn / 64;          // 512
    const int GNC = (int)(NC / 1024);  // 4096

    // ---- weight prep + counting-sort CSR build ----
    k_wprep_big<<<1024, 256, 0, stream>>>(W011, W012, WT);
    WSmall wsm;
    for (int i = 0; i < 4; ++i) {
        wsm.p[3*i + 0] = ecW1[i];
        wsm.p[3*i + 1] = ecW1[i] + 16384;
        wsm.p[3*i + 2] = ecW2[i];
    }
    wsm.p[12] = sageWl; wsm.p[13] = sageWr;
    k_wprep_small<<<896, 256, 0, stream>>>(wsm, (_Float16*)WTs);
    k_zero<<<(2 * 6 * NNn) / 1024, 256, 0, stream>>>((float*)hist);  // hist + fill
    k_hist<<<EEe / 256, 256, 0, stream>>>(attr, edst, hist);
    k_scan_a<<<768, 256, 0, stream>>>(hist, base, bsum);
    k_scan_b<<<1, 384, 0, stream>>>(bsum, cnts);
    k_scan_c<<<768, 256, 0, stream>>>(base, bsum);
    k_fill<<<EEe / 256, 256, 0, stream>>>(esrc, edst, attr, base, fill, arena);

    // ---- x = [xv @ W011 + b011 ; xa @ W012 + b012] ----
    k_gemm<<<NVv * TT / 64, 256, 0, stream>>>(xv, W011T, b011, X,
                                              nullptr, nullptr, nullptr, NVv * TT, FDd, 0, 0);
    k_gemm<<<NAa * TT / 64, 256, 0, stream>>>(xa, W012T, b012,
                                              X + (size_t)NVv * TT * CCc,
                                              nullptr, nullptr, nullptr, NAa * TT, FDd, 0, 0);
    // ---- xa_g = relu(x[d] + max in-edge x[s]) (mask 0); S1 fully written ----
    k_csr_vpa<<<2048, 256, 0, stream>>>(X, arena + offs[0], base + 0 * NNn,
                                        hist + 0 * NNn, caps[0], S1);
    // ---- EdgeConv A (mask 1) ----
    k_gemm<<<GN, 256, 0, stream>>>(S1, WTs, ecb1[0], P,
                                   WTs + 16384, V, nullptr, NNn, CCc, 0, 0);
    k_zero<<<GNC, 256, 0, stream>>>(AH);
    k_edge_mlp<<<1024, 256, 0, stream>>>(P, V, WTs + 2 * 16384, ecb2[0],
                                         arena + offs[1], cnts + 1, caps[1], AH);
    k_fc<<<NNn / 4, 256, 0, stream>>>(AH, fcW, fcb, ARES);
    // ---- xv2 (mask 2); XV2 fully written ----
    k_csr_acv<<<2048, 256, 0, stream>>>(X, ARES, arena + offs[2], base + 2 * NNn,
                                        hist + 2 * NNn, caps[2], XV2);
    k_zero<<<GNC, 256, 0, stream>>>(XO);
    // ---- three branches ----
    for (int b = 0; b < 3; ++b) {
        int j = 3 + b;
        const _Float16* Wd = WTs + (3 * (b + 1)) * 16384;
        k_gemm<<<GN, 256, 0, stream>>>(XV2, Wd, ecb1[b + 1], P,
                                       Wd + 16384, V, nullptr, NNn, CCc, 0, 0);
        k_zero<<<GNC, 256, 0, stream>>>(AH);
        k_edge_mlp<<<1024, 256, 0, stream>>>(P, V, Wd + 2 * 16384, ecb2[b + 1],
                                             arena + offs[j], cnts + j, caps[j], AH);
        k_csr_mean<<<2048, 256, 0, stream>>>(AH, arena + offs[j], base + j * NNn,
                                             hist + j * NNn, caps[j], S1);
        // xo += relu(S1@Wl + AH@Wr + bl)   (dual-A fused)
        k_gemm<<<GN, 256, 0, stream>>>(S1, WlT, sagebl, XO,
                                       WrT, nullptr, AH, NNn, CCc, 1, 1);
    }
    k_gather<<<out_size / 256, 256, 0, stream>>>(XO, spk, out);
}

// Round 6
// 600.773 us; speedup vs baseline: 2.2126x; 1.3226x over previous
//
#include <hip/hip_runtime.h>
#include <cstdint>
#include <cstddef>

#define NVv 192
#define NAa 64
#define TT 128
#define FDd 1024
#define CCc 128
#define EEe 262144
#define NNn 32768

typedef _Float16 f16x8 __attribute__((ext_vector_type(8)));
typedef float f32x4 __attribute__((ext_vector_type(4)));

// list arena capacities/offsets (int2 units): vpa, aud, acv, m1, m2, m3
#define CAP0 65536
#define CAP1 65536
#define CAP2 65536
#define CAP3 98304
#define CAP4 98304
#define CAP5 147456
#define ARENA_TOTAL (CAP0+CAP1+CAP2+CAP3+CAP4+CAP5)   // 540672

__device__ __forceinline__ void eval_masks(int a, bool m[6]) {
    m[0] = (a == -3); m[1] = (a == -2); m[2] = (a == 3);
    m[3] = (a >= 0) & (a <= 1);
    m[4] = (a >= -1) & (a <= 0);
    m[5] = (a >= -1) & (a <= 1);
}

// ---------------- zero fill (1024 floats / block) ----------------
__global__ __launch_bounds__(256) void k_zero(float* __restrict__ p) {
    size_t i = (size_t)blockIdx.x * 1024 + (size_t)threadIdx.x * 4;
    *(float4*)(p + i) = make_float4(0.f, 0.f, 0.f, 0.f);
}

// ---------------- weight prep: f32 [K][128] -> f16 transposed [128][K] ----------------
__global__ __launch_bounds__(256) void k_wprep_big(
    const float* __restrict__ W011, const float* __restrict__ W012,
    _Float16* __restrict__ dst)
{
    int idx = blockIdx.x * 256 + threadIdx.x;        // 262144
    int which = idx >> 17;
    int r = idx & 131071;
    int n = r >> 10, k = r & 1023;
    const float* src = which ? W012 : W011;
    dst[idx] = (_Float16)src[k * 128 + n];
}

struct WSmall { const float* p[14]; };

__global__ __launch_bounds__(256) void k_wprep_small(WSmall ws, _Float16* __restrict__ dst)
{
    int idx = blockIdx.x * 256 + threadIdx.x;        // 14*16384 = 229376
    int seg = idx >> 14;
    int r = idx & 16383;
    int n = r >> 7, k = r & 127;
    const float* src = ws.p[seg];
    float v = src[k * 128 + n];
    if (seg < 12 && (seg % 3) == 0) v -= src[16384 + k * 128 + n];  // W1diff
    dst[idx] = (_Float16)v;
}

// ---------------- counting sort phase 1: per-dst histogram per mask ----------------
__global__ __launch_bounds__(256) void k_hist(
    const int* __restrict__ attr, const int* __restrict__ edst,
    int* __restrict__ hist)
{
    int e = blockIdx.x * 256 + threadIdx.x;
    int a = attr[e], d = edst[e];
    bool m[6]; eval_masks(a, m);
#pragma unroll
    for (int j = 0; j < 6; ++j)
        if (m[j]) atomicAdd(&hist[j * NNn + d], 1);
}

// ---------------- hierarchical exclusive scan ----------------
__global__ __launch_bounds__(256) void k_scan_a(
    const int* __restrict__ hist, int* __restrict__ base, int* __restrict__ bsum)
{
    __shared__ int wsum[4];
    int bid = blockIdx.x;
    int idx = bid * 256 + threadIdx.x;
    int tid = threadIdx.x, lane = tid & 63, wv = tid >> 6;
    int v = hist[idx];
    int x = v;
#pragma unroll
    for (int off = 1; off < 64; off <<= 1) {
        int y = __shfl_up(x, off, 64);
        if (lane >= off) x += y;
    }
    if (lane == 63) wsum[wv] = x;
    __syncthreads();
    int add = 0;
    for (int w = 0; w < wv; ++w) add += wsum[w];
    base[idx] = add + x - v;
    if (tid == 255) bsum[bid] = add + x;
}

__global__ __launch_bounds__(384) void k_scan_b(int* __restrict__ bsum, int* __restrict__ cnts)
{
    int wv = threadIdx.x >> 6;
    int lane = threadIdx.x & 63;
    int run = 0;
#pragma unroll
    for (int c0 = 0; c0 < 128; c0 += 64) {
        int v = bsum[wv * 128 + c0 + lane];
        int x = v;
#pragma unroll
        for (int off = 1; off < 64; off <<= 1) {
            int y = __shfl_up(x, off, 64);
            if (lane >= off) x += y;
        }
        bsum[wv * 128 + c0 + lane] = run + (x - v);
        run += __shfl(x, 63, 64);
    }
    if (lane == 0) cnts[wv] = run;
}

__global__ __launch_bounds__(256) void k_scan_c(int* __restrict__ base, const int* __restrict__ bsum)
{
    base[blockIdx.x * 256 + threadIdx.x] += bsum[blockIdx.x];
}

// ---------------- fill sorted lists ----------------
__global__ __launch_bounds__(256) void k_fill(
    const int* __restrict__ esrc, const int* __restrict__ edst,
    const int* __restrict__ attr, const int* __restrict__ base,
    int* __restrict__ fill, int2* __restrict__ arena)
{
    int e = blockIdx.x * 256 + threadIdx.x;
    int a = attr[e];
    int s = esrc[e], d = edst[e];
    bool m[6]; eval_masks(a, m);
    const int caps[6] = {CAP0, CAP1, CAP2, CAP3, CAP4, CAP5};
    const int offs[6] = {0, CAP0, CAP0+CAP1, CAP0+CAP1+CAP2,
                         CAP0+CAP1+CAP2+CAP3, CAP0+CAP1+CAP2+CAP3+CAP4};
#pragma unroll
    for (int j = 0; j < 6; ++j) {
        if (m[j]) {
            int pos = base[j * NNn + d] + atomicAdd(&fill[j * NNn + d], 1);
            if (pos < caps[j]) arena[offs[j] + pos] = make_int2(s, d);
        }
    }
}

// ---------------- generic GEMM: out[M,128] = op(A[M,K]@BT^T + bias) ----------------
// dualB: also out2 = A@BT2^T (no bias). f16out: out/out2 are _Float16*.
__global__ __launch_bounds__(256) void k_gemm(
    const float* __restrict__ A, const _Float16* __restrict__ BT,
    const float* __restrict__ bias, void* __restrict__ out,
    const _Float16* __restrict__ BT2, void* __restrict__ out2,
    int M, int K, int do_relu, int f16out)
{
    __shared__ _Float16 Al[64][40];
    __shared__ _Float16 Bl[128][40];
    __shared__ _Float16 Bl2[128][40];
    const int tid  = threadIdx.x;
    const int wave = tid >> 6;
    const int lane = tid & 63;
    const int m0   = blockIdx.x * 64;

    f32x4 acc[8], acc2[8];
#pragma unroll
    for (int i = 0; i < 8; ++i) { acc[i] = (f32x4){0,0,0,0}; acc2[i] = (f32x4){0,0,0,0}; }

    const int ar = tid >> 2;
    const int ak = (tid & 3) * 8;
    const int fr = wave * 16 + (lane & 15);
    const int fk = (lane >> 4) * 8;

    for (int k0 = 0; k0 < K; k0 += 32) {
        const float* asrc = A + (size_t)(m0 + ar) * K + (k0 + ak);
        float4 a0 = *(const float4*)asrc;
        float4 a1 = *(const float4*)(asrc + 4);
        f16x8 av = { (_Float16)a0.x, (_Float16)a0.y, (_Float16)a0.z, (_Float16)a0.w,
                     (_Float16)a1.x, (_Float16)a1.y, (_Float16)a1.z, (_Float16)a1.w };
        *(f16x8*)&Al[ar][ak] = av;
#pragma unroll
        for (int i = 0; i < 2; ++i) {
            int c = tid + i * 256;
            int n = c >> 2, koff = (c & 3) * 8;
            *(f16x8*)&Bl[n][koff] = *(const f16x8*)(BT + (size_t)n * K + k0 + koff);
            if (out2)
                *(f16x8*)&Bl2[n][koff] = *(const f16x8*)(BT2 + (size_t)n * K + k0 + koff);
        }
        __syncthreads();
        f16x8 af = *(const f16x8*)&Al[fr][fk];
#pragma unroll
        for (int nt = 0; nt < 8; ++nt) {
            f16x8 bf = *(const f16x8*)&Bl[nt * 16 + (lane & 15)][fk];
            acc[nt] = __builtin_amdgcn_mfma_f32_16x16x32_f16(af, bf, acc[nt], 0, 0, 0);
        }
        if (out2) {
#pragma unroll
            for (int nt = 0; nt < 8; ++nt) {
                f16x8 bf = *(const f16x8*)&Bl2[nt * 16 + (lane & 15)][fk];
                acc2[nt] = __builtin_amdgcn_mfma_f32_16x16x32_f16(af, bf, acc2[nt], 0, 0, 0);
            }
        }
        __syncthreads();
    }

    const int rbase = wave * 16 + (lane >> 4) * 4;
    const int cbase = lane & 15;
#pragma unroll
    for (int nt = 0; nt < 8; ++nt) {
        int col = nt * 16 + cbase;
        float bv = bias ? bias[col] : 0.f;
#pragma unroll
        for (int rr = 0; rr < 4; ++rr) {
            int gr = m0 + rbase + rr;
            size_t o = (size_t)gr * 128 + col;
            float v = acc[nt][rr] + bv;
            if (do_relu) v = fmaxf(v, 0.f);
            if (f16out) {
                ((_Float16*)out)[o] = (_Float16)v;
                if (out2) ((_Float16*)out2)[o] = (_Float16)acc2[nt][rr];
            } else {
                ((float*)out)[o] = v;
                if (out2) ((float*)out2)[o] = acc2[nt][rr];
            }
        }
    }
}

// ---------------- edge MLP on dst-sorted list (f16 P/V, vectorized gather) ----------------
// r = relu(P[d]+V[s]); h = relu(r@W2 + b2); agg[d] = max over dst-group
__global__ __launch_bounds__(256, 3) void k_edge_mlp(
    const _Float16* __restrict__ P, const _Float16* __restrict__ V,
    const _Float16* __restrict__ W2T, const float* __restrict__ b2,
    const int2* __restrict__ list, const int* __restrict__ cntp, int cap,
    float* __restrict__ agg)
{
    __shared__ _Float16 Rl[64][136];        // r tile, then reused for h tile
    __shared__ _Float16 W2l[128][136];
    __shared__ float b2l[128];
    __shared__ int2 eSD[64];
    __shared__ unsigned char gstart[66];
    __shared__ int gdst[64];
    __shared__ int ngrS;

    int cnt = min(*cntp, cap);
    int ntiles = (cnt + 63) >> 6;
    if ((int)blockIdx.x >= ntiles) return;

    const int tid  = threadIdx.x;
    const int wave = tid >> 6;
    const int lane = tid & 63;

    // stage W2^T once per block
#pragma unroll
    for (int i = 0; i < 8; ++i) {
        int c = tid + i * 256;
        int n = c >> 4, koff = (c & 15) * 8;
        *(f16x8*)&W2l[n][koff] = *(const f16x8*)(W2T + n * 128 + koff);
    }
    if (tid < 128) b2l[tid] = b2[tid];

    const int col   = tid & 127;
    const int half  = tid >> 7;
    const int frow  = wave * 16 + (lane & 15);
    const int fq    = (lane >> 4) * 8;
    const int rbase = wave * 16 + (lane >> 4) * 4;
    const int cbase = lane & 15;
    const int rrow  = tid >> 4;          // 0..15: edge sub-row for vector gather
    const int rch   = (tid & 15) * 8;    // f16 chunk offset

    for (int t = blockIdx.x; t < ntiles; t += gridDim.x) {
        __syncthreads();                       // LDS reuse guard
        if (tid < 64) {
            int e = t * 64 + tid;
            eSD[tid] = (e < cnt) ? list[e] : make_int2(0, -1);
        }
        __syncthreads();
        // group boundaries (wave 0)
        if (tid < 64) {
            int d = eSD[tid].y;
            bool flag = (tid == 0) || (d != eSD[tid - 1].y);
            unsigned long long bm = __ballot(flag);
            int rank = (int)__popcll(bm & ((1ull << tid) - 1ull));
            if (flag) { gstart[rank] = (unsigned char)tid; gdst[rank] = d; }
            if (tid == 0) {
                int ng = (int)__popcll(bm);
                ngrS = ng;
                gstart[ng] = 64;
            }
        }
        // build r tile: 16 lanes per edge row, f16x8 vector loads
#pragma unroll
        for (int p = 0; p < 4; ++p) {
            int i = p * 16 + rrow;
            int2 sd = eSD[i];
            f16x8 rv = {0, 0, 0, 0, 0, 0, 0, 0};
            if (sd.y >= 0) {
                f16x8 pv = *(const f16x8*)(P + (size_t)sd.y * 128 + rch);
                f16x8 vv = *(const f16x8*)(V + (size_t)sd.x * 128 + rch);
                rv = pv + vv;
#pragma unroll
                for (int q = 0; q < 8; ++q)
                    rv[q] = (rv[q] > (_Float16)0.f) ? rv[q] : (_Float16)0.f;
            }
            *(f16x8*)&Rl[i][rch] = rv;
        }
        __syncthreads();

        f32x4 acc[8];
#pragma unroll
        for (int i = 0; i < 8; ++i) acc[i] = (f32x4){0,0,0,0};
#pragma unroll
        for (int t4 = 0; t4 < 4; ++t4) {
            f16x8 af = *(const f16x8*)&Rl[frow][t4 * 32 + fq];
#pragma unroll
            for (int nt = 0; nt < 8; ++nt) {
                f16x8 bf = *(const f16x8*)&W2l[nt * 16 + (lane & 15)][t4 * 32 + fq];
                acc[nt] = __builtin_amdgcn_mfma_f32_16x16x32_f16(af, bf, acc[nt], 0, 0, 0);
            }
        }
        __syncthreads();
        // h = relu(acc + b2) back into Rl
#pragma unroll
        for (int nt = 0; nt < 8; ++nt) {
            int c2 = nt * 16 + cbase;
            float bv = b2l[c2];
#pragma unroll
            for (int rr = 0; rr < 4; ++rr)
                Rl[rbase + rr][c2] = (_Float16)fmaxf(acc[nt][rr] + bv, 0.f);
        }
        __syncthreads();
        // segmented max per dst-group
        int ng = ngrS;
        for (int g = half; g < ng; g += 2) {
            int s = gstart[g], e = gstart[g + 1];
            int d = gdst[g];
            if (d < 0) continue;
            float m = 0.f;
            for (int i = s; i < e; ++i)
                m = fmaxf(m, (float)Rl[i][col]);
            size_t o = (size_t)d * 128 + col;
            if (s == 0 || e == 64)
                atomicMax((unsigned int*)&agg[o], __float_as_uint(m));
            else
                agg[o] = m;
        }
    }
}

// ---------------- CSR gather-reduce kernels ----------------
// vpa: out[d] = relu(x[d] + max in-edge x[src]) (empty -> 0)
__global__ __launch_bounds__(256) void k_csr_vpa(
    const float* __restrict__ X, const int2* __restrict__ list,
    const int* __restrict__ base, const int* __restrict__ cntarr, int cap,
    float* __restrict__ S)
{
    int col = threadIdx.x & 127;
    int sub = threadIdx.x >> 7;
    for (int d = blockIdx.x * 2 + sub; d < NNn; d += gridDim.x * 2) {
        int c = cntarr[d];
        float v = 0.f;
        if (c > 0) {
            int b = base[d];
            int end = min(b + c, cap);
            float mx = -3.0e38f;
            for (int i = b; i < end; ++i)
                mx = fmaxf(mx, X[(size_t)list[i].x * 128 + col]);
            v = fmaxf(X[(size_t)d * 128 + col] + mx, 0.f);
        }
        S[(size_t)d * 128 + col] = v;
    }
}

// acv: out[d] = relu(sum(ares[s]*x[s]) + cnt*x[d]) (empty -> 0)
__global__ __launch_bounds__(256) void k_csr_acv(
    const float* __restrict__ X, const float* __restrict__ ares,
    const int2* __restrict__ list,
    const int* __restrict__ base, const int* __restrict__ cntarr, int cap,
    float* __restrict__ S)
{
    int col = threadIdx.x & 127;
    int sub = threadIdx.x >> 7;
    for (int d = blockIdx.x * 2 + sub; d < NNn; d += gridDim.x * 2) {
        int c = cntarr[d];
        float v = 0.f;
        if (c > 0) {
            int b = base[d];
            int end = min(b + c, cap);
            float s = 0.f;
            for (int i = b; i < end; ++i) {
                int sr = list[i].x;
                s += ares[sr] * X[(size_t)sr * 128 + col];
            }
            v = fmaxf(s + (float)c * X[(size_t)d * 128 + col], 0.f);
        }
        S[(size_t)d * 128 + col] = v;
    }
}

// sage mean at TARGET nodes only + compact AH snapshot
__global__ __launch_bounds__(256) void k_csr_meanc(
    const float* __restrict__ AH, const int2* __restrict__ list,
    const int* __restrict__ basej, const int* __restrict__ histj, int cap,
    const int* __restrict__ spk, int ntarg,
    float* __restrict__ S1c, float* __restrict__ AHc)
{
    int col = threadIdx.x & 127;
    int sub = threadIdx.x >> 7;
    int step = spk[0] * TT;
    for (int ci = blockIdx.x * 2 + sub; ci < ntarg; ci += gridDim.x * 2) {
        int d = (ci >> 7) * step + (ci & 127);
        int c = histj[d];
        float v = 0.f;
        if (c > 0) {
            int b = basej[d];
            int end = min(b + c, cap);
            float s = 0.f;
            for (int i = b; i < end; ++i)
                s += AH[(size_t)list[i].x * 128 + col];
            v = s / (float)c;
        }
        S1c[(size_t)ci * 128 + col] = v;
        AHc[(size_t)ci * 128 + col] = AH[(size_t)d * 128 + col];
    }
}

// ---------------- fc: a_res = a @ fc_W + fc_b ----------------
__global__ __launch_bounds__(256) void k_fc(
    const float* __restrict__ A, const float* __restrict__ W,
    const float* __restrict__ b, float* __restrict__ ares)
{
    int node = blockIdx.x * 4 + (threadIdx.x >> 6);
    int lane = threadIdx.x & 63;
    const float* row = A + (size_t)node * 128;
    float v = row[lane] * W[lane] + row[lane + 64] * W[lane + 64];
#pragma unroll
    for (int off = 32; off > 0; off >>= 1) v += __shfl_down(v, off, 64);
    if (lane == 0) ares[node] = v + b[0];
}

// ---------------- fused SAGE output: d_out = sum_b relu(S1c_b@Wl + AHc_b@Wr + bl) ----------------
__global__ __launch_bounds__(256) void k_sage_out(
    const float* __restrict__ S1c, const float* __restrict__ AHc,
    const _Float16* __restrict__ WlT, const _Float16* __restrict__ WrT,
    const float* __restrict__ bl, float* __restrict__ out, int ntarg)
{
    __shared__ _Float16 Al[64][40];
    __shared__ _Float16 Bl[128][40];
    const int tid  = threadIdx.x;
    const int wave = tid >> 6;
    const int lane = tid & 63;
    const int m0   = blockIdx.x * 64;

    f32x4 accB[8], accO[8];
#pragma unroll
    for (int i = 0; i < 8; ++i) { accB[i] = (f32x4){0,0,0,0}; accO[i] = (f32x4){0,0,0,0}; }

    const int ar = tid >> 2;
    const int ak = (tid & 3) * 8;
    const int fr = wave * 16 + (lane & 15);
    const int fk = (lane >> 4) * 8;
    const int rbase = wave * 16 + (lane >> 4) * 4;
    const int cbase = lane & 15;

    for (int seg = 0; seg < 6; ++seg) {
        int b = seg >> 1, which = seg & 1;
        const float* A = (which ? AHc : S1c) + (size_t)b * ntarg * 128;
        const _Float16* BT = which ? WrT : WlT;
        for (int k0 = 0; k0 < 128; k0 += 32) {
            __syncthreads();
            const float* asrc = A + (size_t)(m0 + ar) * 128 + (k0 + ak);
            float4 a0 = *(const float4*)asrc;
            float4 a1 = *(const float4*)(asrc + 4);
            f16x8 av = { (_Float16)a0.x, (_Float16)a0.y, (_Float16)a0.z, (_Float16)a0.w,
                         (_Float16)a1.x, (_Float16)a1.y, (_Float16)a1.z, (_Float16)a1.w };
            *(f16x8*)&Al[ar][ak] = av;
#pragma unroll
            for (int i = 0; i < 2; ++i) {
                int c = tid + i * 256;
                int n = c >> 2, koff = (c & 3) * 8;
                *(f16x8*)&Bl[n][koff] = *(const f16x8*)(BT + (size_t)n * 128 + k0 + koff);
            }
            __syncthreads();
            f16x8 af = *(const f16x8*)&Al[fr][fk];
#pragma unroll
            for (int nt = 0; nt < 8; ++nt) {
                f16x8 bf = *(const f16x8*)&Bl[nt * 16 + (lane & 15)][fk];
                accB[nt] = __builtin_amdgcn_mfma_f32_16x16x32_f16(af, bf, accB[nt], 0, 0, 0);
            }
        }
        if (which) {
#pragma unroll
            for (int nt = 0; nt < 8; ++nt) {
                int col = nt * 16 + cbase;
                float bv = bl[col];
#pragma unroll
                for (int rr = 0; rr < 4; ++rr) {
                    accO[nt][rr] += fmaxf(accB[nt][rr] + bv, 0.f);
                    accB[nt][rr] = 0.f;
                }
            }
        }
    }
#pragma unroll
    for (int nt = 0; nt < 8; ++nt) {
        int col = nt * 16 + cbase;
#pragma unroll
        for (int rr = 0; rr < 4; ++rr)
            out[(size_t)(m0 + rbase + rr) * 128 + col] = accO[nt][rr];
    }
}

extern "C" void kernel_launch(void* const* d_in, const int* in_sizes, int n_in,
                              void* d_out, int out_size, void* d_ws, size_t ws_size,
                              hipStream_t stream)
{
    (void)in_sizes; (void)n_in; (void)ws_size;
    const float* xv   = (const float*)d_in[0];
    const float* xa   = (const float*)d_in[1];
    const float* W011 = (const float*)d_in[2];
    const float* b011 = (const float*)d_in[3];
    const float* W012 = (const float*)d_in[4];
    const float* b012 = (const float*)d_in[5];
    const float* ecW1[4] = {(const float*)d_in[6],  (const float*)d_in[10],
                            (const float*)d_in[14], (const float*)d_in[18]};
    const float* ecb1[4] = {(const float*)d_in[7],  (const float*)d_in[11],
                            (const float*)d_in[15], (const float*)d_in[19]};
    const float* ecW2[4] = {(const float*)d_in[8],  (const float*)d_in[12],
                            (const float*)d_in[16], (const float*)d_in[20]};
    const float* ecb2[4] = {(const float*)d_in[9],  (const float*)d_in[13],
                            (const float*)d_in[17], (const float*)d_in[21]};
    const float* sageWl = (const float*)d_in[22];
    const float* sagebl = (const float*)d_in[23];
    const float* sageWr = (const float*)d_in[24];
    const float* fcW    = (const float*)d_in[25];
    const float* fcb    = (const float*)d_in[26];
    const int*   esrc   = (const int*)d_in[27];
    const int*   edst   = esrc + EEe;
    const int*   attr   = (const int*)d_in[28];
    const int*   spk    = (const int*)d_in[29];
    float* out = (float*)d_out;
    const int ntarg = out_size >> 7;       // 8192 target nodes

    const size_t NC = (size_t)NNn * CCc;   // 4194304
    float* ws   = (float*)d_ws;
    float* X    = ws;                      // [N,C] f32
    float* S1   = ws + 1 * NC;             // vpa out (full N); later S1c[3] compact
    float* AH   = ws + 2 * NC;             // edge-mlp aggregate (zeroed per use)
    float* XV2  = ws + 3 * NC;
    float* AHc  = ws + 4 * NC;             // compact AH snapshots [3][ntarg][C]
    _Float16* P16 = (_Float16*)(ws + 5 * NC);        // NC f16
    _Float16* V16 = P16 + NC;                        // NC f16
    float* ARES = ws + 6 * NC;             // 32768
    int*   cnts = (int*)(ARES + NNn);      // 16 ints
    int*   bsum = cnts + 16;               // 768 + pad
    int*   hist = bsum + 1024;             // 6*32768
    int*   fill = hist + 6 * NNn;          // 6*32768
    int*   base = fill + 6 * NNn;          // 6*32768
    int2*  arena = (int2*)(base + 6 * NNn);
    _Float16* WT = (_Float16*)(arena + ARENA_TOTAL);

    const int offs[6] = {0, CAP0, CAP0+CAP1, CAP0+CAP1+CAP2,
                         CAP0+CAP1+CAP2+CAP3, CAP0+CAP1+CAP2+CAP3+CAP4};
    const int caps[6] = {CAP0, CAP1, CAP2, CAP3, CAP4, CAP5};

    const _Float16* W011T = WT;
    const _Float16* W012T = WT + 131072;
    const _Float16* WTs   = WT + 262144;
    const _Float16* WlT   = WTs + 12 * 16384;
    const _Float16* WrT   = WTs + 13 * 16384;

    const int GN  = NNn / 64;          // 512
    const int GNC = (int)(NC / 1024);  // 4096

    // ---- weight prep + counting-sort CSR build ----
    k_wprep_big<<<1024, 256, 0, stream>>>(W011, W012, WT);
    WSmall wsm;
    for (int i = 0; i < 4; ++i) {
        wsm.p[3*i + 0] = ecW1[i];
        wsm.p[3*i + 1] = ecW1[i] + 16384;
        wsm.p[3*i + 2] = ecW2[i];
    }
    wsm.p[12] = sageWl; wsm.p[13] = sageWr;
    k_wprep_small<<<896, 256, 0, stream>>>(wsm, (_Float16*)WTs);
    k_zero<<<(2 * 6 * NNn) / 1024, 256, 0, stream>>>((float*)hist);  // hist + fill
    k_hist<<<EEe / 256, 256, 0, stream>>>(attr, edst, hist);
    k_scan_a<<<768, 256, 0, stream>>>(hist, base, bsum);
    k_scan_b<<<1, 384, 0, stream>>>(bsum, cnts);
    k_scan_c<<<768, 256, 0, stream>>>(base, bsum);
    k_fill<<<EEe / 256, 256, 0, stream>>>(esrc, edst, attr, base, fill, arena);

    // ---- x = [xv @ W011 + b011 ; xa @ W012 + b012] ----
    k_gemm<<<NVv * TT / 64, 256, 0, stream>>>(xv, W011T, b011, X,
                                              nullptr, nullptr, NVv * TT, FDd, 0, 0);
    k_gemm<<<NAa * TT / 64, 256, 0, stream>>>(xa, W012T, b012,
                                              X + (size_t)NVv * TT * CCc,
                                              nullptr, nullptr, NAa * TT, FDd, 0, 0);
    // ---- xa_g (mask 0) ----
    k_csr_vpa<<<2048, 256, 0, stream>>>(X, arena + offs[0], base + 0 * NNn,
                                        hist + 0 * NNn, caps[0], S1);
    // ---- EdgeConv A (mask 1): P/V f16 ----
    k_gemm<<<GN, 256, 0, stream>>>(S1, WTs, ecb1[0], P16,
                                   WTs + 16384, V16, NNn, CCc, 0, 1);
    k_zero<<<GNC, 256, 0, stream>>>(AH);
    k_edge_mlp<<<2048, 256, 0, stream>>>(P16, V16, WTs + 2 * 16384, ecb2[0],
                                         arena + offs[1], cnts + 1, caps[1], AH);
    k_fc<<<NNn / 4, 256, 0, stream>>>(AH, fcW, fcb, ARES);
    // ---- xv2 (mask 2) ----
    k_csr_acv<<<2048, 256, 0, stream>>>(X, ARES, arena + offs[2], base + 2 * NNn,
                                        hist + 2 * NNn, caps[2], XV2);
    // ---- three branches (sequential; compact tail) ----
    for (int b = 0; b < 3; ++b) {
        int j = 3 + b;
        const _Float16* Wd = WTs + (3 * (b + 1)) * 16384;
        k_gemm<<<GN, 256, 0, stream>>>(XV2, Wd, ecb1[b + 1], P16,
                                       Wd + 16384, V16, NNn, CCc, 0, 1);
        k_zero<<<GNC, 256, 0, stream>>>(AH);
        k_edge_mlp<<<2048, 256, 0, stream>>>(P16, V16, Wd + 2 * 16384, ecb2[b + 1],
                                             arena + offs[j], cnts + j, caps[j], AH);
        k_csr_meanc<<<2048, 256, 0, stream>>>(AH, arena + offs[j], base + j * NNn,
                                              hist + j * NNn, caps[j], spk, ntarg,
                                              S1 + (size_t)b * ntarg * 128,
                                              AHc + (size_t)b * ntarg * 128);
    }
    // ---- fused SAGE epilogue -> d_out ----
    k_sage_out<<<ntarg / 64, 256, 0, stream>>>(S1, AHc, WlT, WrT, sagebl, out, ntarg);
}

// Round 8
// 550.341 us; speedup vs baseline: 2.4154x; 1.0916x over previous
//
#include <hip/hip_runtime.h>
#include <cstdint>
#include <cstddef>

#define NVv 192
#define NAa 64
#define TT 128
#define FDd 1024
#define CCc 128
#define EEe 262144
#define NNn 32768

typedef _Float16 f16x8 __attribute__((ext_vector_type(8)));
typedef float f32x4 __attribute__((ext_vector_type(4)));

// list arena capacities/offsets (int2 units): vpa, aud, acv, m1, m2, m3
#define CAP0 65536
#define CAP1 65536
#define CAP2 65536
#define CAP3 98304
#define CAP4 98304
#define CAP5 147456
#define ARENA_TOTAL (CAP0+CAP1+CAP2+CAP3+CAP4+CAP5)   // 540672

__device__ __forceinline__ void eval_masks(int a, bool m[6]) {
    m[0] = (a == -3); m[1] = (a == -2); m[2] = (a == 3);
    m[3] = (a >= 0) & (a <= 1);
    m[4] = (a >= -1) & (a <= 0);
    m[5] = (a >= -1) & (a <= 1);
}

// ---------------- zero fill (1024 floats / block) ----------------
__global__ __launch_bounds__(256) void k_zero(float* __restrict__ p) {
    size_t i = (size_t)blockIdx.x * 1024 + (size_t)threadIdx.x * 4;
    *(float4*)(p + i) = make_float4(0.f, 0.f, 0.f, 0.f);
}

// zero AH rows that edge_mlp will NOT fully overwrite with plain stores:
// degree-0 rows (stay 0) and rows whose CSR run takes the atomicMax path
// (starts at, ends at, or crosses a 64-edge tile boundary).
__global__ __launch_bounds__(256) void k_zero_need(
    const int* __restrict__ histj, const int* __restrict__ basej,
    float* __restrict__ AH)
{
    int col = threadIdx.x & 127, sub = threadIdx.x >> 7;
    for (int d = blockIdx.x * 2 + sub; d < NNn; d += gridDim.x * 2) {
        int c = histj[d];
        bool need;
        if (c == 0) need = true;
        else {
            int b = basej[d], e = b + c;
            need = ((b & 63) == 0) || ((e & 63) == 0) || ((b >> 6) != ((e - 1) >> 6));
        }
        if (need) AH[(size_t)d * 128 + col] = 0.f;
    }
}

// ---------------- weight prep: f32 [K][128] -> f16 transposed [128][K] ----------------
__global__ __launch_bounds__(256) void k_wprep_big(
    const float* __restrict__ W011, const float* __restrict__ W012,
    _Float16* __restrict__ dst)
{
    int idx = blockIdx.x * 256 + threadIdx.x;        // 262144
    int which = idx >> 17;
    int r = idx & 131071;
    int n = r >> 10, k = r & 1023;
    const float* src = which ? W012 : W011;
    dst[idx] = (_Float16)src[k * 128 + n];
}

struct WSmall { const float* p[14]; };

__global__ __launch_bounds__(256) void k_wprep_small(WSmall ws, _Float16* __restrict__ dst)
{
    int idx = blockIdx.x * 256 + threadIdx.x;        // 14*16384 = 229376
    int seg = idx >> 14;
    int r = idx & 16383;
    int n = r >> 7, k = r & 127;
    const float* src = ws.p[seg];
    float v = src[k * 128 + n];
    if (seg < 12 && (seg % 3) == 0) v -= src[16384 + k * 128 + n];  // W1diff
    dst[idx] = (_Float16)v;
}

// ---------------- counting sort phase 1: per-dst histogram per mask ----------------
__global__ __launch_bounds__(256) void k_hist(
    const int* __restrict__ attr, const int* __restrict__ edst,
    int* __restrict__ hist)
{
    int e = blockIdx.x * 256 + threadIdx.x;
    int a = attr[e], d = edst[e];
    bool m[6]; eval_masks(a, m);
#pragma unroll
    for (int j = 0; j < 6; ++j)
        if (m[j]) atomicAdd(&hist[j * NNn + d], 1);
}

// ---------------- hierarchical exclusive scan ----------------
__global__ __launch_bounds__(256) void k_scan_a(
    const int* __restrict__ hist, int* __restrict__ base, int* __restrict__ bsum)
{
    __shared__ int wsum[4];
    int bid = blockIdx.x;
    int idx = bid * 256 + threadIdx.x;
    int tid = threadIdx.x, lane = tid & 63, wv = tid >> 6;
    int v = hist[idx];
    int x = v;
#pragma unroll
    for (int off = 1; off < 64; off <<= 1) {
        int y = __shfl_up(x, off, 64);
        if (lane >= off) x += y;
    }
    if (lane == 63) wsum[wv] = x;
    __syncthreads();
    int add = 0;
    for (int w = 0; w < wv; ++w) add += wsum[w];
    base[idx] = add + x - v;
    if (tid == 255) bsum[bid] = add + x;
}

__global__ __launch_bounds__(384) void k_scan_b(int* __restrict__ bsum, int* __restrict__ cnts)
{
    int wv = threadIdx.x >> 6;
    int lane = threadIdx.x & 63;
    int run = 0;
#pragma unroll
    for (int c0 = 0; c0 < 128; c0 += 64) {
        int v = bsum[wv * 128 + c0 + lane];
        int x = v;
#pragma unroll
        for (int off = 1; off < 64; off <<= 1) {
            int y = __shfl_up(x, off, 64);
            if (lane >= off) x += y;
        }
        bsum[wv * 128 + c0 + lane] = run + (x - v);
        run += __shfl(x, 63, 64);
    }
    if (lane == 0) cnts[wv] = run;
}

__global__ __launch_bounds__(256) void k_scan_c(int* __restrict__ base, const int* __restrict__ bsum)
{
    base[blockIdx.x * 256 + threadIdx.x] += bsum[blockIdx.x];
}

// ---------------- fill sorted lists ----------------
__global__ __launch_bounds__(256) void k_fill(
    const int* __restrict__ esrc, const int* __restrict__ edst,
    const int* __restrict__ attr, const int* __restrict__ base,
    int* __restrict__ fill, int2* __restrict__ arena)
{
    int e = blockIdx.x * 256 + threadIdx.x;
    int a = attr[e];
    int s = esrc[e], d = edst[e];
    bool m[6]; eval_masks(a, m);
    const int caps[6] = {CAP0, CAP1, CAP2, CAP3, CAP4, CAP5};
    const int offs[6] = {0, CAP0, CAP0+CAP1, CAP0+CAP1+CAP2,
                         CAP0+CAP1+CAP2+CAP3, CAP0+CAP1+CAP2+CAP3+CAP4};
#pragma unroll
    for (int j = 0; j < 6; ++j) {
        if (m[j]) {
            int pos = base[j * NNn + d] + atomicAdd(&fill[j * NNn + d], 1);
            if (pos < caps[j]) arena[offs[j] + pos] = make_int2(s, d);
        }
    }
}

// ---------------- fused input projection: X = [xv@W011+b011 ; xa@W012+b012] ----------------
__global__ __launch_bounds__(512) void k_proj(
    const float* __restrict__ xv, const float* __restrict__ xa,
    const _Float16* __restrict__ BTv, const _Float16* __restrict__ BTa,
    const float* __restrict__ bv_, const float* __restrict__ ba_,
    float* __restrict__ X)
{
    __shared__ _Float16 Bl[128][136];
    __shared__ float Hs[8][16][132];
    __shared__ float bb[128];
    const int tid = threadIdx.x, wave = tid >> 6, lane = tid & 63;
    const int blk = blockIdx.x;
    const float* A; const _Float16* BT; const float* bias; int mbase, obase;
    if (blk < 192) { A = xv; BT = BTv; bias = bv_; mbase = blk * 128; obase = mbase; }
    else { A = xa; BT = BTa; bias = ba_; mbase = (blk - 192) * 128; obase = 24576 + mbase; }
    if (tid < 128) bb[tid] = bias[tid];

    const int mrow = mbase + wave * 16 + (lane & 15);
    const int fk   = (lane >> 4) * 8;
    f32x4 acc[8];
#pragma unroll
    for (int i = 0; i < 8; ++i) acc[i] = (f32x4){0,0,0,0};

    for (int kc = 0; kc < 8; ++kc) {
        __syncthreads();
#pragma unroll
        for (int it = 0; it < 4; ++it) {
            int c = it * 512 + tid;
            int n = c >> 4, koff = (c & 15) * 8;
            *(f16x8*)&Bl[n][koff] = *(const f16x8*)(BT + (size_t)n * 1024 + kc * 128 + koff);
        }
        __syncthreads();
        f16x8 af[4];
#pragma unroll
        for (int t4 = 0; t4 < 4; ++t4) {
            const float* asrc = A + (size_t)mrow * 1024 + kc * 128 + t4 * 32 + fk;
            float4 a0 = *(const float4*)asrc;
            float4 a1 = *(const float4*)(asrc + 4);
            af[t4] = (f16x8){ (_Float16)a0.x, (_Float16)a0.y, (_Float16)a0.z, (_Float16)a0.w,
                              (_Float16)a1.x, (_Float16)a1.y, (_Float16)a1.z, (_Float16)a1.w };
        }
#pragma unroll
        for (int t4 = 0; t4 < 4; ++t4)
#pragma unroll
            for (int nt = 0; nt < 8; ++nt) {
                f16x8 bf = *(const f16x8*)&Bl[nt * 16 + (lane & 15)][t4 * 32 + fk];
                acc[nt] = __builtin_amdgcn_mfma_f32_16x16x32_f16(af[t4], bf, acc[nt], 0, 0, 0);
            }
    }
    const int cbase = lane & 15, rloc = (lane >> 4) * 4;
#pragma unroll
    for (int nt = 0; nt < 8; ++nt) {
        int c2 = nt * 16 + cbase;
        float bvv = bb[c2];
#pragma unroll
        for (int rr = 0; rr < 4; ++rr)
            Hs[wave][rloc + rr][c2] = acc[nt][rr] + bvv;
    }
#pragma unroll
    for (int it = 0; it < 8; ++it) {
        int id = it * 64 + lane;
        int row = id >> 5, off = (id & 31) * 4;
        float4 v = *(float4*)&Hs[wave][row][off];
        *(float4*)&X[(size_t)(obase + wave * 16 + row) * 128 + off] = v;
    }
}

// ---------------- PV GEMM: P = A@BT1^T + b1 (f16), V = A@BT2^T (f16) ----------------
__global__ __launch_bounds__(512) void k_pv(
    const float* __restrict__ A,
    const _Float16* __restrict__ BT1, const float* __restrict__ b1,
    const _Float16* __restrict__ BT2,
    _Float16* __restrict__ P, _Float16* __restrict__ V)
{
    __shared__ _Float16 Bl1[128][136];
    __shared__ _Float16 Bl2[128][136];
    __shared__ _Float16 Hs[8][16][136];
    __shared__ float bb[128];
    const int tid = threadIdx.x, wave = tid >> 6, lane = tid & 63;
    const int r0 = blockIdx.x * 128 + wave * 16;

#pragma unroll
    for (int it = 0; it < 4; ++it) {
        int c = it * 512 + tid;
        int n = c >> 4, koff = (c & 15) * 8;
        *(f16x8*)&Bl1[n][koff] = *(const f16x8*)(BT1 + (size_t)n * 128 + koff);
        *(f16x8*)&Bl2[n][koff] = *(const f16x8*)(BT2 + (size_t)n * 128 + koff);
    }
    if (tid < 128) bb[tid] = b1[tid];
    __syncthreads();

    const int fk = (lane >> 4) * 8;
    const int mrow = r0 + (lane & 15);
    f16x8 af[4];
#pragma unroll
    for (int t4 = 0; t4 < 4; ++t4) {
        const float* asrc = A + (size_t)mrow * 128 + t4 * 32 + fk;
        float4 a0 = *(const float4*)asrc;
        float4 a1 = *(const float4*)(asrc + 4);
        af[t4] = (f16x8){ (_Float16)a0.x, (_Float16)a0.y, (_Float16)a0.z, (_Float16)a0.w,
                          (_Float16)a1.x, (_Float16)a1.y, (_Float16)a1.z, (_Float16)a1.w };
    }
    f32x4 acc1[8], acc2[8];
#pragma unroll
    for (int i = 0; i < 8; ++i) { acc1[i] = (f32x4){0,0,0,0}; acc2[i] = (f32x4){0,0,0,0}; }
#pragma unroll
    for (int t4 = 0; t4 < 4; ++t4)
#pragma unroll
        for (int nt = 0; nt < 8; ++nt) {
            f16x8 bf1 = *(const f16x8*)&Bl1[nt * 16 + (lane & 15)][t4 * 32 + fk];
            f16x8 bf2 = *(const f16x8*)&Bl2[nt * 16 + (lane & 15)][t4 * 32 + fk];
            acc1[nt] = __builtin_amdgcn_mfma_f32_16x16x32_f16(af[t4], bf1, acc1[nt], 0, 0, 0);
            acc2[nt] = __builtin_amdgcn_mfma_f32_16x16x32_f16(af[t4], bf2, acc2[nt], 0, 0, 0);
        }

    const int cbase = lane & 15, rloc = (lane >> 4) * 4;
#pragma unroll
    for (int nt = 0; nt < 8; ++nt) {
        int c2 = nt * 16 + cbase;
        float bvv = bb[c2];
#pragma unroll
        for (int rr = 0; rr < 4; ++rr)
            Hs[wave][rloc + rr][c2] = (_Float16)(acc1[nt][rr] + bvv);
    }
#pragma unroll
    for (int it = 0; it < 4; ++it) {
        int id = it * 64 + lane;
        int row = id >> 4, koff = (id & 15) * 8;
        *(f16x8*)&P[(size_t)(r0 + row) * 128 + koff] = *(f16x8*)&Hs[wave][row][koff];
    }
#pragma unroll
    for (int nt = 0; nt < 8; ++nt) {
        int c2 = nt * 16 + cbase;
#pragma unroll
        for (int rr = 0; rr < 4; ++rr)
            Hs[wave][rloc + rr][c2] = (_Float16)acc2[nt][rr];
    }
#pragma unroll
    for (int it = 0; it < 4; ++it) {
        int id = it * 64 + lane;
        int row = id >> 4, koff = (id & 15) * 8;
        *(f16x8*)&V[(size_t)(r0 + row) * 128 + koff] = *(f16x8*)&Hs[wave][row][koff];
    }
}

// ---------------- edge MLP on dst-sorted list (f16 P/V, vectorized gather) ----------------
__global__ __launch_bounds__(256, 3) void k_edge_mlp(
    const _Float16* __restrict__ P, const _Float16* __restrict__ V,
    const _Float16* __restrict__ W2T, const float* __restrict__ b2,
    const int2* __restrict__ list, const int* __restrict__ cntp, int cap,
    float* __restrict__ agg)
{
    __shared__ _Float16 Rl[64][136];
    __shared__ _Float16 W2l[128][136];
    __shared__ float b2l[128];
    __shared__ int2 eSD[64];
    __shared__ unsigned char gstart[66];
    __shared__ int gdst[64];
    __shared__ int ngrS;

    int cnt = min(*cntp, cap);
    int ntiles = (cnt + 63) >> 6;
    if ((int)blockIdx.x >= ntiles) return;

    const int tid  = threadIdx.x;
    const int wave = tid >> 6;
    const int lane = tid & 63;

#pragma unroll
    for (int i = 0; i < 8; ++i) {
        int c = tid + i * 256;
        int n = c >> 4, koff = (c & 15) * 8;
        *(f16x8*)&W2l[n][koff] = *(const f16x8*)(W2T + n * 128 + koff);
    }
    if (tid < 128) b2l[tid] = b2[tid];

    const int col   = tid & 127;
    const int half  = tid >> 7;
    const int frow  = wave * 16 + (lane & 15);
    const int fq    = (lane >> 4) * 8;
    const int rbase = wave * 16 + (lane >> 4) * 4;
    const int cbase = lane & 15;
    const int rrow  = tid >> 4;
    const int rch   = (tid & 15) * 8;

    for (int t = blockIdx.x; t < ntiles; t += gridDim.x) {
        __syncthreads();
        if (tid < 64) {
            int e = t * 64 + tid;
            eSD[tid] = (e < cnt) ? list[e] : make_int2(0, -1);
        }
        __syncthreads();
        if (tid < 64) {
            int d = eSD[tid].y;
            bool flag = (tid == 0) || (d != eSD[tid - 1].y);
            unsigned long long bm = __ballot(flag);
            int rank = (int)__popcll(bm & ((1ull << tid) - 1ull));
            if (flag) { gstart[rank] = (unsigned char)tid; gdst[rank] = d; }
            if (tid == 0) {
                int ng = (int)__popcll(bm);
                ngrS = ng;
                gstart[ng] = 64;
            }
        }
#pragma unroll
        for (int p = 0; p < 4; ++p) {
            int i = p * 16 + rrow;
            int2 sd = eSD[i];
            f16x8 rv = {0, 0, 0, 0, 0, 0, 0, 0};
            if (sd.y >= 0) {
                f16x8 pv = *(const f16x8*)(P + (size_t)sd.y * 128 + rch);
                f16x8 vv = *(const f16x8*)(V + (size_t)sd.x * 128 + rch);
                rv = pv + vv;
#pragma unroll
                for (int q = 0; q < 8; ++q)
                    rv[q] = (rv[q] > (_Float16)0.f) ? rv[q] : (_Float16)0.f;
            }
            *(f16x8*)&Rl[i][rch] = rv;
        }
        __syncthreads();

        f32x4 acc[8];
#pragma unroll
        for (int i = 0; i < 8; ++i) acc[i] = (f32x4){0,0,0,0};
#pragma unroll
        for (int t4 = 0; t4 < 4; ++t4) {
            f16x8 af = *(const f16x8*)&Rl[frow][t4 * 32 + fq];
#pragma unroll
            for (int nt = 0; nt < 8; ++nt) {
                f16x8 bf = *(const f16x8*)&W2l[nt * 16 + (lane & 15)][t4 * 32 + fq];
                acc[nt] = __builtin_amdgcn_mfma_f32_16x16x32_f16(af, bf, acc[nt], 0, 0, 0);
            }
        }
        __syncthreads();
#pragma unroll
        for (int nt = 0; nt < 8; ++nt) {
            int c2 = nt * 16 + cbase;
            float bv = b2l[c2];
#pragma unroll
            for (int rr = 0; rr < 4; ++rr)
                Rl[rbase + rr][c2] = (_Float16)fmaxf(acc[nt][rr] + bv, 0.f);
        }
        __syncthreads();
        int ng = ngrS;
        for (int g = half; g < ng; g += 2) {
            int s = gstart[g], e = gstart[g + 1];
            int d = gdst[g];
            if (d < 0) continue;
            float m = 0.f;
            for (int i = s; i < e; ++i)
                m = fmaxf(m, (float)Rl[i][col]);
            size_t o = (size_t)d * 128 + col;
            if (s == 0 || e == 64)
                atomicMax((unsigned int*)&agg[o], __float_as_uint(m));
            else
                agg[o] = m;
        }
    }
}

// ---------------- CSR gather-reduce kernels ----------------
__global__ __launch_bounds__(256) void k_csr_vpa(
    const float* __restrict__ X, const int2* __restrict__ list,
    const int* __restrict__ base, const int* __restrict__ cntarr, int cap,
    float* __restrict__ S)
{
    int col = threadIdx.x & 127;
    int sub = threadIdx.x >> 7;
    for (int d = blockIdx.x * 2 + sub; d < NNn; d += gridDim.x * 2) {
        int c = cntarr[d];
        float v = 0.f;
        if (c > 0) {
            int b = base[d];
            int end = min(b + c, cap);
            float mx = -3.0e38f;
            for (int i = b; i < end; ++i)
                mx = fmaxf(mx, X[(size_t)list[i].x * 128 + col]);
            v = fmaxf(X[(size_t)d * 128 + col] + mx, 0.f);
        }
        S[(size_t)d * 128 + col] = v;
    }
}

__global__ __launch_bounds__(256) void k_csr_acv(
    const float* __restrict__ X, const float* __restrict__ ares,
    const int2* __restrict__ list,
    const int* __restrict__ base, const int* __restrict__ cntarr, int cap,
    float* __restrict__ S)
{
    int col = threadIdx.x & 127;
    int sub = threadIdx.x >> 7;
    for (int d = blockIdx.x * 2 + sub; d < NNn; d += gridDim.x * 2) {
        int c = cntarr[d];
        float v = 0.f;
        if (c > 0) {
            int b = base[d];
            int end = min(b + c, cap);
            float s = 0.f;
            for (int i = b; i < end; ++i) {
                int sr = list[i].x;
                s += ares[sr] * X[(size_t)sr * 128 + col];
            }
            v = fmaxf(s + (float)c * X[(size_t)d * 128 + col], 0.f);
        }
        S[(size_t)d * 128 + col] = v;
    }
}

__global__ __launch_bounds__(256) void k_csr_meanc(
    const float* __restrict__ AH, const int2* __restrict__ list,
    const int* __restrict__ basej, const int* __restrict__ histj, int cap,
    const int* __restrict__ spk, int ntarg,
    float* __restrict__ S1c, float* __restrict__ AHc)
{
    int col = threadIdx.x & 127;
    int sub = threadIdx.x >> 7;
    int step = spk[0] * TT;
    for (int ci = blockIdx.x * 2 + sub; ci < ntarg; ci += gridDim.x * 2) {
        int d = (ci >> 7) * step + (ci & 127);
        int c = histj[d];
        float v = 0.f;
        if (c > 0) {
            int b = basej[d];
            int end = min(b + c, cap);
            float s = 0.f;
            for (int i = b; i < end; ++i)
                s += AH[(size_t)list[i].x * 128 + col];
            v = s / (float)c;
        }
        S1c[(size_t)ci * 128 + col] = v;
        AHc[(size_t)ci * 128 + col] = AH[(size_t)d * 128 + col];
    }
}

// ---------------- fc: a_res = a @ fc_W + fc_b ----------------
__global__ __launch_bounds__(256) void k_fc(
    const float* __restrict__ A, const float* __restrict__ W,
    const float* __restrict__ b, float* __restrict__ ares)
{
    int node = blockIdx.x * 4 + (threadIdx.x >> 6);
    int lane = threadIdx.x & 63;
    const float* row = A + (size_t)node * 128;
    float v = row[lane] * W[lane] + row[lane + 64] * W[lane + 64];
#pragma unroll
    for (int off = 32; off > 0; off >>= 1) v += __shfl_down(v, off, 64);
    if (lane == 0) ares[node] = v + b[0];
}

// ---------------- fused SAGE output: d_out = sum_b relu(S1c_b@Wl + AHc_b@Wr + bl) ----------------
__global__ __launch_bounds__(256) void k_sage_out(
    const float* __restrict__ S1c, const float* __restrict__ AHc,
    const _Float16* __restrict__ WlT, const _Float16* __restrict__ WrT,
    const float* __restrict__ bl, float* __restrict__ out, int ntarg)
{
    __shared__ _Float16 Al[64][40];
    __shared__ _Float16 Bl[128][40];
    const int tid  = threadIdx.x;
    const int wave = tid >> 6;
    const int lane = tid & 63;
    const int m0   = blockIdx.x * 64;

    f32x4 accB[8], accO[8];
#pragma unroll
    for (int i = 0; i < 8; ++i) { accB[i] = (f32x4){0,0,0,0}; accO[i] = (f32x4){0,0,0,0}; }

    const int ar = tid >> 2;
    const int ak = (tid & 3) * 8;
    const int fr = wave * 16 + (lane & 15);
    const int fk = (lane >> 4) * 8;
    const int rbase = wave * 16 + (lane >> 4) * 4;
    const int cbase = lane & 15;

    for (int seg = 0; seg < 6; ++seg) {
        int b = seg >> 1, which = seg & 1;
        const float* A = (which ? AHc : S1c) + (size_t)b * ntarg * 128;
        const _Float16* BT = which ? WrT : WlT;
        for (int k0 = 0; k0 < 128; k0 += 32) {
            __syncthreads();
            const float* asrc = A + (size_t)(m0 + ar) * 128 + (k0 + ak);
            float4 a0 = *(const float4*)asrc;
            float4 a1 = *(const float4*)(asrc + 4);
            f16x8 av = { (_Float16)a0.x, (_Float16)a0.y, (_Float16)a0.z, (_Float16)a0.w,
                         (_Float16)a1.x, (_Float16)a1.y, (_Float16)a1.z, (_Float16)a1.w };
            *(f16x8*)&Al[ar][ak] = av;
#pragma unroll
            for (int i = 0; i < 2; ++i) {
                int c = tid + i * 256;
                int n = c >> 2, koff = (c & 3) * 8;
                *(f16x8*)&Bl[n][koff] = *(const f16x8*)(BT + (size_t)n * 128 + k0 + koff);
            }
            __syncthreads();
            f16x8 af = *(const f16x8*)&Al[fr][fk];
#pragma unroll
            for (int nt = 0; nt < 8; ++nt) {
                f16x8 bf = *(const f16x8*)&Bl[nt * 16 + (lane & 15)][fk];
                accB[nt] = __builtin_amdgcn_mfma_f32_16x16x32_f16(af, bf, accB[nt], 0, 0, 0);
            }
        }
        if (which) {
#pragma unroll
            for (int nt = 0; nt < 8; ++nt) {
                int col = nt * 16 + cbase;
                float bv = bl[col];
#pragma unroll
                for (int rr = 0; rr < 4; ++rr) {
                    accO[nt][rr] += fmaxf(accB[nt][rr] + bv, 0.f);
                    accB[nt][rr] = 0.f;
                }
            }
        }
    }
#pragma unroll
    for (int nt = 0; nt < 8; ++nt) {
        int col = nt * 16 + cbase;
#pragma unroll
        for (int rr = 0; rr < 4; ++rr)
            out[(size_t)(m0 + rbase + rr) * 128 + col] = accO[nt][rr];
    }
}

extern "C" void kernel_launch(void* const* d_in, const int* in_sizes, int n_in,
                              void* d_out, int out_size, void* d_ws, size_t ws_size,
                              hipStream_t stream)
{
    (void)in_sizes; (void)n_in; (void)ws_size;
    const float* xv   = (const float*)d_in[0];
    const float* xa   = (const float*)d_in[1];
    const float* W011 = (const float*)d_in[2];
    const float* b011 = (const float*)d_in[3];
    const float* W012 = (const float*)d_in[4];
    const float* b012 = (const float*)d_in[5];
    const float* ecW1[4] = {(const float*)d_in[6],  (const float*)d_in[10],
                            (const float*)d_in[14], (const float*)d_in[18]};
    const float* ecb1[4] = {(const float*)d_in[7],  (const float*)d_in[11],
                            (const float*)d_in[15], (const float*)d_in[19]};
    const float* ecW2[4] = {(const float*)d_in[8],  (const float*)d_in[12],
                            (const float*)d_in[16], (const float*)d_in[20]};
    const float* ecb2[4] = {(const float*)d_in[9],  (const float*)d_in[13],
                            (const float*)d_in[17], (const float*)d_in[21]};
    const float* sageWl = (const float*)d_in[22];
    const float* sagebl = (const float*)d_in[23];
    const float* sageWr = (const float*)d_in[24];
    const float* fcW    = (const float*)d_in[25];
    const float* fcb    = (const float*)d_in[26];
    const int*   esrc   = (const int*)d_in[27];
    const int*   edst   = esrc + EEe;
    const int*   attr   = (const int*)d_in[28];
    const int*   spk    = (const int*)d_in[29];
    float* out = (float*)d_out;
    const int ntarg = out_size >> 7;       // 8192 target nodes

    const size_t NC = (size_t)NNn * CCc;   // 4194304
    float* ws   = (float*)d_ws;
    float* X    = ws;                      // [N,C] f32
    float* S1   = ws + 1 * NC;             // vpa out (full N); later S1c[3] compact
    float* AH   = ws + 2 * NC;             // edge-mlp aggregate
    float* XV2  = ws + 3 * NC;
    float* AHc  = ws + 4 * NC;             // compact AH snapshots [3][ntarg][C]
    _Float16* P16 = (_Float16*)(ws + 5 * NC);        // NC f16
    _Float16* V16 = P16 + NC;                        // NC f16
    float* ARES = ws + 6 * NC;             // 32768
    int*   cnts = (int*)(ARES + NNn);      // 16 ints
    int*   bsum = cnts + 16;               // 768 + pad
    int*   hist = bsum + 1024;             // 6*32768
    int*   fill = hist + 6 * NNn;          // 6*32768
    int*   base = fill + 6 * NNn;          // 6*32768
    int2*  arena = (int2*)(base + 6 * NNn);
    _Float16* WT = (_Float16*)(arena + ARENA_TOTAL);

    const int offs[6] = {0, CAP0, CAP0+CAP1, CAP0+CAP1+CAP2,
                         CAP0+CAP1+CAP2+CAP3, CAP0+CAP1+CAP2+CAP3+CAP4};
    const int caps[6] = {CAP0, CAP1, CAP2, CAP3, CAP4, CAP5};

    const _Float16* W011T = WT;
    const _Float16* W012T = WT + 131072;
    const _Float16* WTs   = WT + 262144;
    const _Float16* WlT   = WTs + 12 * 16384;
    const _Float16* WrT   = WTs + 13 * 16384;

    // ---- weight prep + counting-sort CSR build ----
    k_wprep_big<<<1024, 256, 0, stream>>>(W011, W012, WT);
    WSmall wsm;
    for (int i = 0; i < 4; ++i) {
        wsm.p[3*i + 0] = ecW1[i];
        wsm.p[3*i + 1] = ecW1[i] + 16384;
        wsm.p[3*i + 2] = ecW2[i];
    }
    wsm.p[12] = sageWl; wsm.p[13] = sageWr;
    k_wprep_small<<<896, 256, 0, stream>>>(wsm, (_Float16*)WTs);
    k_zero<<<(2 * 6 * NNn) / 1024, 256, 0, stream>>>((float*)hist);  // hist + fill
    k_hist<<<EEe / 256, 256, 0, stream>>>(attr, edst, hist);
    k_scan_a<<<768, 256, 0, stream>>>(hist, base, bsum);
    k_scan_b<<<1, 384, 0, stream>>>(bsum, cnts);
    k_scan_c<<<768, 256, 0, stream>>>(base, bsum);
    k_fill<<<EEe / 256, 256, 0, stream>>>(esrc, edst, attr, base, fill, arena);

    // ---- fused input projection ----
    k_proj<<<256, 512, 0, stream>>>(xv, xa, W011T, W012T, b011, b012, X);
    // ---- xa_g (mask 0) ----
    k_csr_vpa<<<2048, 256, 0, stream>>>(X, arena + offs[0], base + 0 * NNn,
                                        hist + 0 * NNn, caps[0], S1);
    // ---- EdgeConv A (mask 1): P/V f16 ----
    k_pv<<<256, 512, 0, stream>>>(S1, WTs, ecb1[0], WTs + 16384, P16, V16);
    k_zero_need<<<2048, 256, 0, stream>>>(hist + 1 * NNn, base + 1 * NNn, AH);
    k_edge_mlp<<<2048, 256, 0, stream>>>(P16, V16, WTs + 2 * 16384, ecb2[0],
                                         arena + offs[1], cnts + 1, caps[1], AH);
    k_fc<<<NNn / 4, 256, 0, stream>>>(AH, fcW, fcb, ARES);
    // ---- xv2 (mask 2) ----
    k_csr_acv<<<2048, 256, 0, stream>>>(X, ARES, arena + offs[2], base + 2 * NNn,
                                        hist + 2 * NNn, caps[2], XV2);
    // ---- three branches ----
    for (int b = 0; b < 3; ++b) {
        int j = 3 + b;
        const _Float16* Wd = WTs + (3 * (b + 1)) * 16384;
        k_pv<<<256, 512, 0, stream>>>(XV2, Wd, ecb1[b + 1], Wd + 16384, P16, V16);
        k_zero_need<<<2048, 256, 0, stream>>>(hist + j * NNn, base + j * NNn, AH);
        k_edge_mlp<<<2048, 256, 0, stream>>>(P16, V16, Wd + 2 * 16384, ecb2[b + 1],
                                             arena + offs[j], cnts + j, caps[j], AH);
        k_csr_meanc<<<2048, 256, 0, stream>>>(AH, arena + offs[j], base + j * NNn,
                                              hist + j * NNn, caps[j], spk, ntarg,
                                              S1 + (size_t)b * ntarg * 128,
                                              AHc + (size_t)b * ntarg * 128);
    }
    // ---- fused SAGE epilogue -> d_out ----
    k_sage_out<<<ntarg / 64, 256, 0, stream>>>(S1, AHc, WlT, WrT, sagebl, out, ntarg);
}